// Round 6
// baseline (272.227 us; speedup 1.0000x reference)
//
#include <hip/hip_runtime.h>

#define NHh 16

typedef unsigned short ushortT;
typedef __attribute__((ext_vector_type(8))) short short8;
typedef __attribute__((ext_vector_type(4))) float floatx4;

__device__ __forceinline__ ushortT f2bf(float x) {
    union { float f; unsigned int u; } cv; cv.f = x;
    unsigned int u = cv.u;
    unsigned int r = u + 0x7fffu + ((u >> 16) & 1u);
    return (ushortT)(r >> 16);
}

// truncating pack of two fp32 -> packed bf16x2 (cheap; used for P which is in [0,1])
__device__ __forceinline__ unsigned pack2_trunc(float a, float b) {
    union { float f; unsigned u; } ua, ub;
    ua.f = a; ub.f = b;
    return (ub.u & 0xffff0000u) | (ua.u >> 16);
}

__device__ __forceinline__ void gload_lds16(const ushortT* g, ushortT* l) {
    __builtin_amdgcn_global_load_lds(
        (const __attribute__((address_space(1))) void*)g,
        (__attribute__((address_space(3))) void*)l, 16, 0, 0);
}

// ---------------- fp32 -> bf16 converters ----------------
__global__ __launch_bounds__(256) void cvt_x(const float* __restrict__ in,
                                             ushortT* __restrict__ out, int n4) {
    int i = blockIdx.x * 256 + threadIdx.x;
    if (i >= n4) return;
    float4 f = ((const float4*)in)[i];
    uint2 o;
    o.x = (unsigned)f2bf(f.x) | ((unsigned)f2bf(f.y) << 16);
    o.y = (unsigned)f2bf(f.z) | ((unsigned)f2bf(f.w) << 16);
    ((uint2*)out)[i] = o;
}

// Wq/Wk/Wv stacked contiguously into Wall[3072][1024]; Wo separate.
__global__ __launch_bounds__(256) void cvt_w(const float* __restrict__ W0, const float* __restrict__ W1,
                                             const float* __restrict__ W2, const float* __restrict__ W3,
                                             ushortT* __restrict__ Wall, ushortT* __restrict__ Wob, int n4) {
    int z = blockIdx.y;
    const float* in = (z == 0) ? W0 : (z == 1) ? W1 : (z == 2) ? W2 : W3;
    ushortT* out = (z < 3) ? (Wall + (size_t)z * 1048576) : Wob;
    int i = blockIdx.x * 256 + threadIdx.x;
    if (i >= n4) return;
    float4 f = ((const float4*)in)[i];
    uint2 o;
    o.x = (unsigned)f2bf(f.x) | ((unsigned)f2bf(f.y) << 16);
    o.y = (unsigned)f2bf(f.z) | ((unsigned)f2bf(f.w) << 16);
    ((uint2*)out)[i] = o;
}

// ======== stacked QKV GEMM, software-pipelined: 256x192, 512 blocks = 2 exact rounds ====
// Pipeline unit = K=32 half-tile. Per tile T:
//  u0: RD(T,ks1)->nxt | MFMA(T,ks0) on cur | lgkm(0) | vmcnt(0) | barrier
//  u1: STAGE(T+2)->buf[T&1] | RD(T+1,ks0)->cur | MFMA(T,ks1) on nxt | lgkm(0)
// ds_reads issue before the MFMA burst -> LDS latency + drains hide under ~931cyc MFMA.
__global__ __launch_bounds__(512, 1) void qkv_pipe(
        const ushortT* __restrict__ X, const ushortT* __restrict__ Wall,
        const float* __restrict__ b0, const float* __restrict__ b1, const float* __restrict__ b2,
        ushortT* __restrict__ Qo, ushortT* __restrict__ Ko, ushortT* __restrict__ Vo) {
    __shared__ __align__(16) ushortT As[2 * 16384];   // 64 KB
    __shared__ __align__(16) ushortT Bs[2 * 12288];   // 48 KB

    const int l = blockIdx.x;
    const int xcd = l & 7;
    const int j = l >> 3;             // 0..63
    const int mg = j >> 4;            // 0..3
    const int nt = j & 15;            // 0..15
    const int arow0 = (mg * 8 + xcd) * 256;   // X token-panel grouped per XCD
    const int brow0 = nt * 192;               // stacked out-dim tile

    const int tid = threadIdx.x;
    const int lane = tid & 63;
    const int w = tid >> 6;
    const int wr = w >> 2;            // 0..1 (M)
    const int wc = w & 3;             // 0..3 (N)
    const int qd = lane >> 4, ln = lane & 15;

    const ushortT* srcA[4]; const ushortT* srcB[3];
    int oA[4], oB[3];
#pragma unroll
    for (int k = 0; k < 4; k++) {
        int o = k * 8192 + tid * 16;
        int rowblk = o >> 11, ks = (o >> 10) & 1, r = (o >> 6) & 15;
        int c2 = ((o >> 4) & 3) ^ ((r >> 3) << 1);
        srcA[k] = X + (size_t)(arow0 + rowblk * 16 + r) * 1024 + ks * 32 + c2 * 8;
        oA[k] = o;
    }
#pragma unroll
    for (int k = 0; k < 3; k++) {
        int o = k * 8192 + tid * 16;
        int rowblk = o >> 11, ks = (o >> 10) & 1, r = (o >> 6) & 15;
        int c2 = ((o >> 4) & 3) ^ ((r >> 3) << 1);
        srcB[k] = Wall + (size_t)(brow0 + rowblk * 16 + r) * 1024 + ks * 32 + c2 * 8;
        oB[k] = o;
    }

    floatx4 acc[8][3];
#pragma unroll
    for (int i = 0; i < 8; i++)
#pragma unroll
        for (int jj = 0; jj < 3; jj++) acc[i][jj] = (floatx4){0.f, 0.f, 0.f, 0.f};

    auto STAGE = [&](int buf) {
#pragma unroll
        for (int k = 0; k < 4; k++) {
            gload_lds16(srcA[k], (ushortT*)((char*)As + buf * 32768 + oA[k]));
            srcA[k] += 64;
        }
#pragma unroll
        for (int k = 0; k < 3; k++) {
            gload_lds16(srcB[k], (ushortT*)((char*)Bs + buf * 24576 + oB[k]));
            srcB[k] += 64;
        }
    };

    const int lnc = ln * 64 + ((qd ^ ((ln >> 3) << 1)) * 16);  // swizzled in-subtile byte off

    short8 a0[8], bf0[3], a1[8], bf1[3];     // ping-pong frag sets (static names)

    auto RD = [&](short8 (&af)[8], short8 (&bf)[3], const char* Ab, const char* Bb, int ksb) {
#pragma unroll
        for (int mi = 0; mi < 8; mi++)
            af[mi] = *(const short8*)(Ab + (wr * 8 + mi) * 2048 + ksb + lnc);
#pragma unroll
        for (int ni = 0; ni < 3; ni++)
            bf[ni] = *(const short8*)(Bb + (wc * 3 + ni) * 2048 + ksb + lnc);
    };
    auto MM = [&](short8 (&af)[8], short8 (&bf)[3]) {
        __builtin_amdgcn_s_setprio(1);
#pragma unroll
        for (int mi = 0; mi < 8; mi++)
#pragma unroll
            for (int ni = 0; ni < 3; ni++)
                acc[mi][ni] = __builtin_amdgcn_mfma_f32_16x16x32_bf16(af[mi], bf[ni], acc[mi][ni], 0, 0, 0);
        __builtin_amdgcn_s_setprio(0);
    };

    // prologue: tiles 0,1 staged; tile0 landed; frags(0,ks0) in regs
    STAGE(0); STAGE(1);
    asm volatile("s_waitcnt vmcnt(7)" ::: "memory");
    __builtin_amdgcn_s_barrier();
    RD(a0, bf0, (const char*)As, (const char*)Bs, 0);
    asm volatile("s_waitcnt lgkmcnt(0)" ::: "memory");
    __builtin_amdgcn_sched_barrier(0);

    for (int T = 0; T < 16; T++) {
        const char* Ab = (const char*)As + (T & 1) * 32768;
        const char* Bb = (const char*)Bs + (T & 1) * 24576;
        const char* An = (const char*)As + ((T + 1) & 1) * 32768;
        const char* Bn = (const char*)Bs + ((T + 1) & 1) * 24576;
        // ---- u0 ----
        RD(a1, bf1, Ab, Bb, 1024);               // frags(T,ks1)
        __builtin_amdgcn_sched_barrier(0);
        MM(a0, bf0);                             // MFMA(T,ks0)
        asm volatile("s_waitcnt lgkmcnt(0)" ::: "memory");   // (T,ks1) in regs; buf reads done
        asm volatile("s_waitcnt vmcnt(0)" ::: "memory");     // tile T+1 landed (issued last iter)
        __builtin_amdgcn_sched_barrier(0);
        __builtin_amdgcn_s_barrier();            // all waves done reading buf[T&1]
        // ---- u1 ----
        if (T < 14) STAGE(T & 1);                // tile T+2 -> buf[T&1] (now safe)
        if (T < 15) RD(a0, bf0, An, Bn, 0);      // frags(T+1,ks0)
        __builtin_amdgcn_sched_barrier(0);
        MM(a1, bf1);                             // MFMA(T,ks1)
        asm volatile("s_waitcnt lgkmcnt(0)" ::: "memory");
        __builtin_amdgcn_sched_barrier(0);
    }

    // epilogue (unchanged from round 4/5 — verified)
#pragma unroll
    for (int ni = 0; ni < 3; ni++) {
        int n = brow0 + wc * 48 + ni * 16 + ln;   // stacked out dim 0..3071
        int z = n >> 10;
        int col = n & 1023;
        int h = col >> 6, d = col & 63;
        const float* bias = (z == 0) ? b0 : (z == 1) ? b1 : b2;
        float bb = bias[col];
        if (z == 2) {
#pragma unroll
            for (int mi = 0; mi < 8; mi++) {
                int m = arow0 + wr * 128 + mi * 16 + qd * 4;   // token (4-aligned)
                int b = m >> 10, s = m & 1023;
                ushort4 pk;
                pk.x = f2bf(acc[mi][ni][0] + bb);
                pk.y = f2bf(acc[mi][ni][1] + bb);
                pk.z = f2bf(acc[mi][ni][2] + bb);
                pk.w = f2bf(acc[mi][ni][3] + bb);
                *(ushort4*)&Vo[((size_t)(b * NHh + h) * 64 + d) * 1024 + s] = pk;
            }
        } else {
            ushortT* Out = z ? Ko : Qo;
#pragma unroll
            for (int mi = 0; mi < 8; mi++) {
#pragma unroll
                for (int r2 = 0; r2 < 4; r2++) {
                    int m = arow0 + wr * 128 + mi * 16 + qd * 4 + r2;  // token
                    int b = m >> 10, s = m & 1023;
                    Out[(size_t)((b * NHh + h) * 1024 + s) * 64 + d] =
                        f2bf(acc[mi][ni][r2] + bb);
                }
            }
        }
    }
}

// ======== out-proj GEMM, same pipeline: 256x128, 256 blocks = 1 exact round ========
__global__ __launch_bounds__(512, 1) void oproj_pipe(const ushortT* __restrict__ A,
        const ushortT* __restrict__ Wt, const float* __restrict__ bias, float* __restrict__ Pj) {
    __shared__ __align__(16) ushortT As[2 * 16384];   // 64 KB
    __shared__ __align__(16) ushortT Bs[2 * 8192];    // 32 KB

    const int l = blockIdx.x;
    const int xcd = l & 7;
    const int j = l >> 3;             // 0..31
    const int tid = threadIdx.x;
    const int lane = tid & 63;
    const int w = tid >> 6;
    const int wr = w >> 1, wc = w & 1;
    const int qd = lane >> 4, ln = lane & 15;

    const int arow0 = ((j & 3) * 8 + xcd) * 256;  // ctx token-panel per XCD
    const int brow0 = (j >> 2) * 128;             // Wo out-dim tile

    const ushortT* srcA[4]; const ushortT* srcB[2];
    int oA[4], oB[2];
#pragma unroll
    for (int k = 0; k < 4; k++) {
        int o = k * 8192 + tid * 16;
        int rowblk = o >> 11, ks = (o >> 10) & 1, r = (o >> 6) & 15;
        int c2 = ((o >> 4) & 3) ^ ((r >> 3) << 1);
        srcA[k] = A + (size_t)(arow0 + rowblk * 16 + r) * 1024 + ks * 32 + c2 * 8;
        oA[k] = o;
    }
#pragma unroll
    for (int k = 0; k < 2; k++) {
        int o = k * 8192 + tid * 16;
        int rowblk = o >> 11, ks = (o >> 10) & 1, r = (o >> 6) & 15;
        int c2 = ((o >> 4) & 3) ^ ((r >> 3) << 1);
        srcB[k] = Wt + (size_t)(brow0 + rowblk * 16 + r) * 1024 + ks * 32 + c2 * 8;
        oB[k] = o;
    }

    floatx4 acc[4][4];
#pragma unroll
    for (int i = 0; i < 4; i++)
#pragma unroll
        for (int jj = 0; jj < 4; jj++) acc[i][jj] = (floatx4){0.f, 0.f, 0.f, 0.f};

    auto STAGE = [&](int buf) {
#pragma unroll
        for (int k = 0; k < 4; k++) {
            gload_lds16(srcA[k], (ushortT*)((char*)As + buf * 32768 + oA[k]));
            srcA[k] += 64;
        }
#pragma unroll
        for (int k = 0; k < 2; k++) {
            gload_lds16(srcB[k], (ushortT*)((char*)Bs + buf * 16384 + oB[k]));
            srcB[k] += 64;
        }
    };

    const int lnc = ln * 64 + ((qd ^ ((ln >> 3) << 1)) * 16);

    short8 a0[4], bf0[4], a1[4], bf1[4];

    auto RD = [&](short8 (&af)[4], short8 (&bf)[4], const char* Ab, const char* Bb, int ksb) {
#pragma unroll
        for (int mi = 0; mi < 4; mi++)
            af[mi] = *(const short8*)(Ab + (mi * 4 + wr) * 2048 + ksb + lnc);
#pragma unroll
        for (int ni = 0; ni < 4; ni++)
            bf[ni] = *(const short8*)(Bb + (ni * 2 + wc) * 2048 + ksb + lnc);
    };
    auto MM = [&](short8 (&af)[4], short8 (&bf)[4]) {
        __builtin_amdgcn_s_setprio(1);
#pragma unroll
        for (int mi = 0; mi < 4; mi++)
#pragma unroll
            for (int ni = 0; ni < 4; ni++)
                acc[mi][ni] = __builtin_amdgcn_mfma_f32_16x16x32_bf16(af[mi], bf[ni], acc[mi][ni], 0, 0, 0);
        __builtin_amdgcn_s_setprio(0);
    };

    STAGE(0); STAGE(1);
    asm volatile("s_waitcnt vmcnt(6)" ::: "memory");
    __builtin_amdgcn_s_barrier();
    RD(a0, bf0, (const char*)As, (const char*)Bs, 0);
    asm volatile("s_waitcnt lgkmcnt(0)" ::: "memory");
    __builtin_amdgcn_sched_barrier(0);

    for (int T = 0; T < 16; T++) {
        const char* Ab = (const char*)As + (T & 1) * 32768;
        const char* Bb = (const char*)Bs + (T & 1) * 16384;
        const char* An = (const char*)As + ((T + 1) & 1) * 32768;
        const char* Bn = (const char*)Bs + ((T + 1) & 1) * 16384;
        // u0
        RD(a1, bf1, Ab, Bb, 1024);
        __builtin_amdgcn_sched_barrier(0);
        MM(a0, bf0);
        asm volatile("s_waitcnt lgkmcnt(0)" ::: "memory");
        asm volatile("s_waitcnt vmcnt(0)" ::: "memory");
        __builtin_amdgcn_sched_barrier(0);
        __builtin_amdgcn_s_barrier();
        // u1
        if (T < 14) STAGE(T & 1);
        if (T < 15) RD(a0, bf0, An, Bn, 0);
        __builtin_amdgcn_sched_barrier(0);
        MM(a1, bf1);
        asm volatile("s_waitcnt lgkmcnt(0)" ::: "memory");
        __builtin_amdgcn_sched_barrier(0);
    }

#pragma unroll
    for (int ni = 0; ni < 4; ni++) {
        int n = brow0 + ni * 32 + wc * 16 + ln;
        float bb = bias[n];
#pragma unroll
        for (int mi = 0; mi < 4; mi++) {
#pragma unroll
            for (int r2 = 0; r2 < 4; r2++) {
                int m = arow0 + mi * 64 + wr * 16 + qd * 4 + r2;
                Pj[(size_t)m * 1024 + n] = acc[mi][ni][r2] + bb;
            }
        }
    }
}

// ---------------- flash attention v2: 8 waves x 32 q, s-half phases, small Ps ----------------
__global__ __launch_bounds__(512, 4) void attn8(const ushortT* __restrict__ Q,
        const ushortT* __restrict__ K, const ushortT* __restrict__ Vg_t,
        const float* __restrict__ mask, ushortT* __restrict__ ctx) {
    __shared__ __align__(16) ushortT Ks[128 * 64];      // 16 KB
    __shared__ __align__(16) ushortT Vt[64 * 128];      // 16 KB
    __shared__ __align__(16) ushortT Ps[8][32 * 36];    // 18 KB

    const int tid = threadIdx.x;
    const int lane = tid & 63;
    const int w = tid >> 6;           // 0..7
    const int qd = lane >> 4;
    const int ln = lane & 15;
    const int l = blockIdx.x;
    const int bh = l & 127;
    const int b = bh >> 4;
    const int h = bh & 15;
    const int qb = l >> 7;

    const ushortT* Qg = Q + (size_t)bh * 65536;
    const ushortT* Kg = K + (size_t)bh * 65536;
    const ushortT* Vg = Vg_t + (size_t)bh * 65536;
    const float* mrow = mask + b * 1024;
    const float LOG2E = 1.4426950408889634f;
    const float SCL = 0.125f * 1.4426950408889634f;   // fold 1/sqrt(64) and log2e

    // resident Q B-fragments: q = qb*256 + w*32 + g*16 + ln
    short8 qf[2][2];
#pragma unroll
    for (int g = 0; g < 2; g++)
#pragma unroll
        for (int ks = 0; ks < 2; ks++)
            qf[g][ks] = *(const short8*)(Qg + (size_t)(qb * 256 + w * 32 + g * 16 + ln) * 64 + ks * 32 + qd * 8);

    float lst[2] = {0.f, 0.f};        // per-lane partial row-sum (qd-reduce deferred)
    floatx4 accO[2][4];
#pragma unroll
    for (int g = 0; g < 2; g++)
#pragma unroll
        for (int j = 0; j < 4; j++) accO[g][j] = (floatx4){0.f, 0.f, 0.f, 0.f};

    // staging lane geometry (8 waves x 2 chunks each)
    const int ksr = lane >> 3;          // K: s-subrow within 8-row group
    const int kc  = lane & 7;           // K: chunk index (8 x 16B per 128B row)
    const int vdr = lane >> 4;          // V: d-subrow within 4-row group
    const int vcc = lane & 15;          // V: chunk index (16 x 16B per 256B row)

    for (int kt = 0; kt < 8; ++kt) {
        __syncthreads();   // all waves done reading Ks/Vt of kt-1

        // stage K tile [128 s][64 d], chunk g2 of row s at slot g2^(s&7)
#pragma unroll
        for (int ii = 0; ii < 2; ii++) {
            int i = w * 2 + ii;
            int srow = i * 8 + ksr;
            gload_lds16(Kg + (size_t)(kt * 128 + srow) * 64 + (kc ^ ksr) * 8,
                        Ks + i * 512 + lane * 8);
        }
        // stage V^T tile [64 d][128 s], chunk g2 of row d at slot g2^(d&15)
#pragma unroll
        for (int ii = 0; ii < 2; ii++) {
            int i = w * 2 + ii;
            int d = i * 4 + vdr;
            gload_lds16(Vg + (size_t)d * 1024 + kt * 128 + (vcc ^ (d & 15)) * 8,
                        Vt + i * 512 + lane * 8);
        }

        __syncthreads();   // tiles ready

#pragma unroll
        for (int h2 = 0; h2 < 2; ++h2) {
#pragma unroll
            for (int mip = 0; mip < 2; ++mip) {
                // ---- QK^T over this 32-s half (S^T frags: col=q=ln, row=s) ----
                floatx4 sv[2][2];
#pragma unroll
                for (int mi2 = 0; mi2 < 2; mi2++)
#pragma unroll
                    for (int g = 0; g < 2; g++) sv[mi2][g] = (floatx4){0.f, 0.f, 0.f, 0.f};
#pragma unroll
                for (int ks = 0; ks < 2; ks++) {
                    short8 af[2];
#pragma unroll
                    for (int mi2 = 0; mi2 < 2; mi2++)
                        af[mi2] = *(const short8*)&Ks[(h2 * 64 + mip * 32 + mi2 * 16 + ln) * 64 +
                                                      (((ks * 4 + qd) ^ (ln & 7)) * 8)];
#pragma unroll
                    for (int mi2 = 0; mi2 < 2; mi2++)
#pragma unroll
                        for (int g = 0; g < 2; g++)
                            sv[mi2][g] = __builtin_amdgcn_mfma_f32_16x16x32_bf16(af[mi2], qf[g][ks], sv[mi2][g], 0, 0, 0);
                }

                // ---- softmax-lite: p = exp2(s*SCL + mask*LOG2E), write Ps half ----
#pragma unroll
                for (int mi2 = 0; mi2 < 2; mi2++) {
                    floatx4 m4 = *(const floatx4*)(mrow + kt * 128 + h2 * 64 + mip * 32 + mi2 * 16 + qd * 4);
                    floatx4 mm;
                    mm[0] = m4[0] * LOG2E; mm[1] = m4[1] * LOG2E;
                    mm[2] = m4[2] * LOG2E; mm[3] = m4[3] * LOG2E;
#pragma unroll
                    for (int g = 0; g < 2; g++) {
                        float p0 = __builtin_amdgcn_exp2f(sv[mi2][g][0] * SCL + mm[0]);
                        float p1 = __builtin_amdgcn_exp2f(sv[mi2][g][1] * SCL + mm[1]);
                        float p2 = __builtin_amdgcn_exp2f(sv[mi2][g][2] * SCL + mm[2]);
                        float p3 = __builtin_amdgcn_exp2f(sv[mi2][g][3] * SCL + mm[3]);
                        lst[g] += (p0 + p1) + (p2 + p3);
                        uint2 wv;
                        wv.x = pack2_trunc(p0, p1);
                        wv.y = pack2_trunc(p2, p3);
                        *(uint2*)&Ps[w][(g * 16 + ln) * 36 + mi2 * 16 + qd * 4] = wv;
                    }
                }

                // ---- PV for k-slice = this s-half (per-wave Ps, no barrier) ----
                short8 ap[2], bv[4];
#pragma unroll
                for (int g = 0; g < 2; g++)
                    ap[g] = *(const short8*)&Ps[w][(g * 16 + ln) * 36 + qd * 8];
#pragma unroll
                for (int j = 0; j < 4; j++)
                    bv[j] = *(const short8*)&Vt[(j * 16 + ln) * 128 +
                                                (((h2 * 8 + mip * 4 + qd) ^ ln) * 8)];
#pragma unroll
                for (int g = 0; g < 2; g++)
#pragma unroll
                    for (int j = 0; j < 4; j++)
                        accO[g][j] = __builtin_amdgcn_mfma_f32_16x16x32_bf16(ap[g], bv[j], accO[g][j], 0, 0, 0);
            }
        }
    }

    // deferred qd-reduction of row sums (linear, so once at the end)
#pragma unroll
    for (int g = 0; g < 2; g++) {
        lst[g] += __shfl_xor(lst[g], 16, 64);
        lst[g] += __shfl_xor(lst[g], 32, 64);
    }

    // epilogue: divide by l (lane transpose once) and store ctx [b][s=q][h*64+d]
#pragma unroll
    for (int g = 0; g < 2; g++) {
#pragma unroll
        for (int r = 0; r < 4; r++) {
            float lv = __shfl(lst[g], qd * 4 + r, 64);
            float linv = 1.f / lv;
            int q = qb * 256 + w * 32 + g * 16 + qd * 4 + r;
#pragma unroll
            for (int j = 0; j < 4; j++) {
                int d = j * 16 + ln;
                ctx[((size_t)(b * 1024 + q)) * 1024 + h * 64 + d] = f2bf(accO[g][j][r] * linv);
            }
        }
    }
}

// ---------------- residual + LayerNorm ----------------
__global__ __launch_bounds__(256) void ln_kernel(const float* __restrict__ Pj, const float* __restrict__ X,
        const float* __restrict__ gamma, const float* __restrict__ beta, float* __restrict__ out) {
    __shared__ float red[8];
    int row = blockIdx.x;
    int t = threadIdx.x;
    const float4 p4 = ((const float4*)(Pj + (size_t)row * 1024))[t];
    const float4 x4 = ((const float4*)(X + (size_t)row * 1024))[t];
    float r0 = p4.x + x4.x, r1 = p4.y + x4.y, r2 = p4.z + x4.z, r3 = p4.w + x4.w;
    float s = r0 + r1 + r2 + r3;
    float ss = r0 * r0 + r1 * r1 + r2 * r2 + r3 * r3;
#pragma unroll
    for (int o = 1; o < 64; o <<= 1) { s += __shfl_xor(s, o, 64); ss += __shfl_xor(ss, o, 64); }
    int w = t >> 6;
    if ((t & 63) == 0) { red[w] = s; red[4 + w] = ss; }
    __syncthreads();
    s = red[0] + red[1] + red[2] + red[3];
    ss = red[4] + red[5] + red[6] + red[7];
    float mu = s * (1.f / 1024.f);
    float var = ss * (1.f / 1024.f) - mu * mu;
    float inv = rsqrtf(var + 1e-12f);
    const float4 g4 = ((const float4*)gamma)[t];
    const float4 b4 = ((const float4*)beta)[t];
    float4 o4;
    o4.x = (r0 - mu) * inv * g4.x + b4.x;
    o4.y = (r1 - mu) * inv * g4.y + b4.y;
    o4.z = (r2 - mu) * inv * g4.z + b4.z;
    o4.w = (r3 - mu) * inv * g4.w + b4.w;
    ((float4*)(out + (size_t)row * 1024))[t] = o4;
}

extern "C" void kernel_launch(void* const* d_in, const int* in_sizes, int n_in,
                              void* d_out, int out_size, void* d_ws, size_t ws_size,
                              hipStream_t stream) {
    const float* x     = (const float*)d_in[0];
    const float* mask  = (const float*)d_in[1];
    const float* Wq    = (const float*)d_in[2];
    const float* bq    = (const float*)d_in[3];
    const float* Wk    = (const float*)d_in[4];
    const float* bk    = (const float*)d_in[5];
    const float* Wv    = (const float*)d_in[6];
    const float* bv    = (const float*)d_in[7];
    const float* Wo    = (const float*)d_in[8];
    const float* bo    = (const float*)d_in[9];
    const float* gamma = (const float*)d_in[10];
    const float* beta  = (const float*)d_in[11];
    float* out = (float*)d_out;

    char* ws = (char*)d_ws;
    ushortT* Xb   = (ushortT*)(ws);
    ushortT* Wall = (ushortT*)(ws + (16u << 20));  // stacked Wq|Wk|Wv [3072][1024], 6 MB
    ushortT* Wob  = (ushortT*)(ws + (22u << 20));
    ushortT* Qb   = (ushortT*)(ws + (24u << 20));
    ushortT* Kb   = (ushortT*)(ws + (40u << 20));
    ushortT* Vb   = (ushortT*)(ws + (56u << 20));  // V^T [bh][d][s]
    ushortT* Cb   = (ushortT*)(ws);                // ctx reuses Xb
    float*   Pj   = (float*)(ws + (24u << 20));    // fp32 proj reuses Q/K

    cvt_x<<<8192, 256, 0, stream>>>(x, Xb, 2097152);
    cvt_w<<<dim3(1024, 4), 256, 0, stream>>>(Wq, Wk, Wv, Wo, Wall, Wob, 262144);
    qkv_pipe<<<512, 512, 0, stream>>>(Xb, Wall, bq, bk, bv, Qb, Kb, Vb);
    attn8<<<512, 512, 0, stream>>>(Qb, Kb, Vb, mask, Cb);
    oproj_pipe<<<256, 512, 0, stream>>>(Cb, Wob, bo, Pj);
    ln_kernel<<<8192, 256, 0, stream>>>(Pj, x, gamma, beta, out);
}

// Round 7
// 267.850 us; speedup vs baseline: 1.0163x; 1.0163x over previous
//
#include <hip/hip_runtime.h>

#define NHh 16

typedef unsigned short ushortT;
typedef __attribute__((ext_vector_type(8))) short short8;
typedef __attribute__((ext_vector_type(4))) float floatx4;

__device__ __forceinline__ ushortT f2bf(float x) {
    union { float f; unsigned int u; } cv; cv.f = x;
    unsigned int u = cv.u;
    unsigned int r = u + 0x7fffu + ((u >> 16) & 1u);
    return (ushortT)(r >> 16);
}

// truncating pack of two fp32 -> packed bf16x2 (cheap; used for P which is in [0,1])
__device__ __forceinline__ unsigned pack2_trunc(float a, float b) {
    union { float f; unsigned u; } ua, ub;
    ua.f = a; ub.f = b;
    return (ub.u & 0xffff0000u) | (ua.u >> 16);
}

__device__ __forceinline__ void gload_lds16(const ushortT* g, ushortT* l) {
    __builtin_amdgcn_global_load_lds(
        (const __attribute__((address_space(1))) void*)g,
        (__attribute__((address_space(3))) void*)l, 16, 0, 0);
}

// ---------------- fp32 -> bf16 converter (X + all weights in one dispatch) ----------------
// blocks 0..8191: X (2097152 float4).  blocks 8192..12287: weights, z=(bid-8192)>>10.
__global__ __launch_bounds__(256) void cvt_all(const float* __restrict__ x,
        const float* __restrict__ W0, const float* __restrict__ W1,
        const float* __restrict__ W2, const float* __restrict__ W3,
        ushortT* __restrict__ Xb, ushortT* __restrict__ Wall, ushortT* __restrict__ Wob) {
    int bid = blockIdx.x;
    const float* in; ushortT* out; int i;
    if (bid < 8192) {
        in = x; out = Xb; i = bid * 256 + threadIdx.x;
    } else {
        int z = (bid - 8192) >> 10;
        in = (z == 0) ? W0 : (z == 1) ? W1 : (z == 2) ? W2 : W3;
        out = (z < 3) ? (Wall + (size_t)z * 1048576) : Wob;
        i = ((bid - 8192) & 1023) * 256 + threadIdx.x;
    }
    float4 f = ((const float4*)in)[i];
    uint2 o;
    o.x = (unsigned)f2bf(f.x) | ((unsigned)f2bf(f.y) << 16);
    o.y = (unsigned)f2bf(f.z) | ((unsigned)f2bf(f.w) << 16);
    ((uint2*)out)[i] = o;
}

// ======== stacked QKV GEMM, software-pipelined: 256x192, 512 blocks = 2 exact rounds ====
// (byte-identical structure to round 6 — measured 73.3 us)
__global__ __launch_bounds__(512, 1) void qkv_pipe(
        const ushortT* __restrict__ X, const ushortT* __restrict__ Wall,
        const float* __restrict__ b0, const float* __restrict__ b1, const float* __restrict__ b2,
        ushortT* __restrict__ Qo, ushortT* __restrict__ Ko, ushortT* __restrict__ Vo) {
    __shared__ __align__(16) ushortT As[2 * 16384];   // 64 KB
    __shared__ __align__(16) ushortT Bs[2 * 12288];   // 48 KB

    const int l = blockIdx.x;
    const int xcd = l & 7;
    const int j = l >> 3;             // 0..63
    const int mg = j >> 4;            // 0..3
    const int nt = j & 15;            // 0..15
    const int arow0 = (mg * 8 + xcd) * 256;   // X token-panel grouped per XCD
    const int brow0 = nt * 192;               // stacked out-dim tile

    const int tid = threadIdx.x;
    const int lane = tid & 63;
    const int w = tid >> 6;
    const int wr = w >> 2;            // 0..1 (M)
    const int wc = w & 3;             // 0..3 (N)
    const int qd = lane >> 4, ln = lane & 15;

    const ushortT* srcA[4]; const ushortT* srcB[3];
    int oA[4], oB[3];
#pragma unroll
    for (int k = 0; k < 4; k++) {
        int o = k * 8192 + tid * 16;
        int rowblk = o >> 11, ks = (o >> 10) & 1, r = (o >> 6) & 15;
        int c2 = ((o >> 4) & 3) ^ ((r >> 3) << 1);
        srcA[k] = X + (size_t)(arow0 + rowblk * 16 + r) * 1024 + ks * 32 + c2 * 8;
        oA[k] = o;
    }
#pragma unroll
    for (int k = 0; k < 3; k++) {
        int o = k * 8192 + tid * 16;
        int rowblk = o >> 11, ks = (o >> 10) & 1, r = (o >> 6) & 15;
        int c2 = ((o >> 4) & 3) ^ ((r >> 3) << 1);
        srcB[k] = Wall + (size_t)(brow0 + rowblk * 16 + r) * 1024 + ks * 32 + c2 * 8;
        oB[k] = o;
    }

    floatx4 acc[8][3];
#pragma unroll
    for (int i = 0; i < 8; i++)
#pragma unroll
        for (int jj = 0; jj < 3; jj++) acc[i][jj] = (floatx4){0.f, 0.f, 0.f, 0.f};

    auto STAGE = [&](int buf) {
#pragma unroll
        for (int k = 0; k < 4; k++) {
            gload_lds16(srcA[k], (ushortT*)((char*)As + buf * 32768 + oA[k]));
            srcA[k] += 64;
        }
#pragma unroll
        for (int k = 0; k < 3; k++) {
            gload_lds16(srcB[k], (ushortT*)((char*)Bs + buf * 24576 + oB[k]));
            srcB[k] += 64;
        }
    };

    const int lnc = ln * 64 + ((qd ^ ((ln >> 3) << 1)) * 16);  // swizzled in-subtile byte off

    short8 a0[8], bf0[3], a1[8], bf1[3];     // ping-pong frag sets (static names)

    auto RD = [&](short8 (&af)[8], short8 (&bf)[3], const char* Ab, const char* Bb, int ksb) {
#pragma unroll
        for (int mi = 0; mi < 8; mi++)
            af[mi] = *(const short8*)(Ab + (wr * 8 + mi) * 2048 + ksb + lnc);
#pragma unroll
        for (int ni = 0; ni < 3; ni++)
            bf[ni] = *(const short8*)(Bb + (wc * 3 + ni) * 2048 + ksb + lnc);
    };
    auto MM = [&](short8 (&af)[8], short8 (&bf)[3]) {
        __builtin_amdgcn_s_setprio(1);
#pragma unroll
        for (int mi = 0; mi < 8; mi++)
#pragma unroll
            for (int ni = 0; ni < 3; ni++)
                acc[mi][ni] = __builtin_amdgcn_mfma_f32_16x16x32_bf16(af[mi], bf[ni], acc[mi][ni], 0, 0, 0);
        __builtin_amdgcn_s_setprio(0);
    };

    // prologue: tiles 0,1 staged; tile0 landed; frags(0,ks0) in regs
    STAGE(0); STAGE(1);
    asm volatile("s_waitcnt vmcnt(7)" ::: "memory");
    __builtin_amdgcn_s_barrier();
    RD(a0, bf0, (const char*)As, (const char*)Bs, 0);
    asm volatile("s_waitcnt lgkmcnt(0)" ::: "memory");
    __builtin_amdgcn_sched_barrier(0);

    for (int T = 0; T < 16; T++) {
        const char* Ab = (const char*)As + (T & 1) * 32768;
        const char* Bb = (const char*)Bs + (T & 1) * 24576;
        const char* An = (const char*)As + ((T + 1) & 1) * 32768;
        const char* Bn = (const char*)Bs + ((T + 1) & 1) * 24576;
        // ---- u0 ----
        RD(a1, bf1, Ab, Bb, 1024);               // frags(T,ks1)
        __builtin_amdgcn_sched_barrier(0);
        MM(a0, bf0);                             // MFMA(T,ks0)
        asm volatile("s_waitcnt lgkmcnt(0)" ::: "memory");   // (T,ks1) in regs; buf reads done
        asm volatile("s_waitcnt vmcnt(0)" ::: "memory");     // tile T+1 landed (issued last iter)
        __builtin_amdgcn_sched_barrier(0);
        __builtin_amdgcn_s_barrier();            // all waves done reading buf[T&1]
        // ---- u1 ----
        if (T < 14) STAGE(T & 1);                // tile T+2 -> buf[T&1] (now safe)
        if (T < 15) RD(a0, bf0, An, Bn, 0);      // frags(T+1,ks0)
        __builtin_amdgcn_sched_barrier(0);
        MM(a1, bf1);                             // MFMA(T,ks1)
        asm volatile("s_waitcnt lgkmcnt(0)" ::: "memory");
        __builtin_amdgcn_sched_barrier(0);
    }

    // epilogue (verified in rounds 4-6)
#pragma unroll
    for (int ni = 0; ni < 3; ni++) {
        int n = brow0 + wc * 48 + ni * 16 + ln;   // stacked out dim 0..3071
        int z = n >> 10;
        int col = n & 1023;
        int h = col >> 6, d = col & 63;
        const float* bias = (z == 0) ? b0 : (z == 1) ? b1 : b2;
        float bb = bias[col];
        if (z == 2) {
#pragma unroll
            for (int mi = 0; mi < 8; mi++) {
                int m = arow0 + wr * 128 + mi * 16 + qd * 4;   // token (4-aligned)
                int b = m >> 10, s = m & 1023;
                ushort4 pk;
                pk.x = f2bf(acc[mi][ni][0] + bb);
                pk.y = f2bf(acc[mi][ni][1] + bb);
                pk.z = f2bf(acc[mi][ni][2] + bb);
                pk.w = f2bf(acc[mi][ni][3] + bb);
                *(ushort4*)&Vo[((size_t)(b * NHh + h) * 64 + d) * 1024 + s] = pk;
            }
        } else {
            ushortT* Out = z ? Ko : Qo;
#pragma unroll
            for (int mi = 0; mi < 8; mi++) {
#pragma unroll
                for (int r2 = 0; r2 < 4; r2++) {
                    int m = arow0 + wr * 128 + mi * 16 + qd * 4 + r2;  // token
                    int b = m >> 10, s = m & 1023;
                    Out[(size_t)((b * NHh + h) * 1024 + s) * 64 + d] =
                        f2bf(acc[mi][ni][r2] + bb);
                }
            }
        }
    }
}

// ======== 256x128 GEMM core: 1 phase / K-tile, triple-buffered LDS ring (r3-proven) ========
__device__ __forceinline__ void gemm_core_256x128(
        const ushortT* __restrict__ Ap, const ushortT* __restrict__ Bp,
        int arow0, int brow0, ushortT* As3, ushortT* Bs3,
        int tid, int wr, int wc, int qd, int ln, floatx4 (&acc)[4][4]) {
    const ushortT* srcA[4]; const ushortT* srcB[2];
    int oA[4], oB[2];
#pragma unroll
    for (int k = 0; k < 4; k++) {
        int o = k * 8192 + tid * 16;
        int rowblk = o >> 11, ks = (o >> 10) & 1, r = (o >> 6) & 15;
        int c2 = ((o >> 4) & 3) ^ ((r >> 3) << 1);
        srcA[k] = Ap + (size_t)(arow0 + rowblk * 16 + r) * 1024 + ks * 32 + c2 * 8;
        oA[k] = o;
    }
#pragma unroll
    for (int k = 0; k < 2; k++) {
        int o = k * 8192 + tid * 16;
        int rowblk = o >> 11, ks = (o >> 10) & 1, r = (o >> 6) & 15;
        int c2 = ((o >> 4) & 3) ^ ((r >> 3) << 1);
        srcB[k] = Bp + (size_t)(brow0 + rowblk * 16 + r) * 1024 + ks * 32 + c2 * 8;
        oB[k] = o;
    }
#pragma unroll
    for (int t = 0; t < 2; t++) {
#pragma unroll
        for (int k = 0; k < 4; k++) {
            gload_lds16(srcA[k], (ushortT*)((char*)As3 + t * 32768 + oA[k]));
            srcA[k] += 64;
        }
#pragma unroll
        for (int k = 0; k < 2; k++) {
            gload_lds16(srcB[k], (ushortT*)((char*)Bs3 + t * 16384 + oB[k]));
            srcB[k] += 64;
        }
    }
    asm volatile("s_waitcnt vmcnt(6)" ::: "memory");
    __builtin_amdgcn_s_barrier();

    const int lnc = ln * 64 + ((qd ^ ((ln >> 3) << 1)) * 16);

    int bi = 0, si = 2;
    for (int T = 0; T < 16; T++) {
        const char* Ab = (const char*)As3 + bi * 32768;
        const char* Bb = (const char*)Bs3 + bi * 16384;
        short8 afr[4][2], bfr[4][2];
#pragma unroll
        for (int mi = 0; mi < 4; mi++)
#pragma unroll
            for (int ks = 0; ks < 2; ks++)
                afr[mi][ks] = *(const short8*)(Ab + (mi * 4 + wr) * 2048 + ks * 1024 + lnc);
#pragma unroll
        for (int ni = 0; ni < 4; ni++)
#pragma unroll
            for (int ks = 0; ks < 2; ks++)
                bfr[ni][ks] = *(const short8*)(Bb + (ni * 2 + wc) * 2048 + ks * 1024 + lnc);
        if (T < 14) {
#pragma unroll
            for (int k = 0; k < 4; k++) {
                gload_lds16(srcA[k], (ushortT*)((char*)As3 + si * 32768 + oA[k]));
                srcA[k] += 64;
            }
#pragma unroll
            for (int k = 0; k < 2; k++) {
                gload_lds16(srcB[k], (ushortT*)((char*)Bs3 + si * 16384 + oB[k]));
                srcB[k] += 64;
            }
        }
        __builtin_amdgcn_s_barrier();
        asm volatile("s_waitcnt lgkmcnt(0)" ::: "memory");
        __builtin_amdgcn_sched_barrier(0);
        __builtin_amdgcn_s_setprio(1);
#pragma unroll
        for (int mi = 0; mi < 4; mi++)
#pragma unroll
            for (int ni = 0; ni < 4; ni++)
#pragma unroll
                for (int ks = 0; ks < 2; ks++)
                    acc[mi][ni] = __builtin_amdgcn_mfma_f32_16x16x32_bf16(
                        afr[mi][ks], bfr[ni][ks], acc[mi][ni], 0, 0, 0);
        __builtin_amdgcn_s_setprio(0);
        if (T < 14) { asm volatile("s_waitcnt vmcnt(6)" ::: "memory"); }
        else        { asm volatile("s_waitcnt vmcnt(0)" ::: "memory"); }
        __builtin_amdgcn_s_barrier();
        bi = (bi == 2) ? 0 : bi + 1;
        si = (si == 2) ? 0 : si + 1;
    }
}

// ---------------- out-proj GEMM: 256 blocks = 1 round, residual(+X) fused epilogue ----------
__global__ __launch_bounds__(512, 1) void oproj_gemm3(const ushortT* __restrict__ A,
        const ushortT* __restrict__ Wt, const float* __restrict__ bias,
        const float* __restrict__ Xf, float* __restrict__ Pj) {
    __shared__ __align__(16) ushortT As3[3 * 16384];
    __shared__ __align__(16) ushortT Bs3[3 * 8192];

    const int l = blockIdx.x;
    const int xcd = l & 7;
    const int j = l >> 3;             // 0..31
    const int tid = threadIdx.x;
    const int lane = tid & 63;
    const int w = tid >> 6;
    const int wr = w >> 1, wc = w & 1;
    const int qd = lane >> 4, ln = lane & 15;

    const int arow0 = ((j & 3) * 8 + xcd) * 256;  // ctx token-panel per XCD
    const int brow0 = (j >> 2) * 128;             // Wo out-dim tile

    floatx4 acc[4][4];
#pragma unroll
    for (int i = 0; i < 4; i++)
#pragma unroll
        for (int jj = 0; jj < 4; jj++) acc[i][jj] = (floatx4){0.f, 0.f, 0.f, 0.f};

    gemm_core_256x128(A, Wt, arow0, brow0, As3, Bs3, tid, wr, wc, qd, ln, acc);

#pragma unroll
    for (int ni = 0; ni < 4; ni++) {
        int n = brow0 + ni * 32 + wc * 16 + ln;
        float bb = bias[n];
#pragma unroll
        for (int mi = 0; mi < 4; mi++) {
#pragma unroll
            for (int r2 = 0; r2 < 4; r2++) {
                int m = arow0 + mi * 64 + wr * 16 + qd * 4 + r2;
                Pj[(size_t)m * 1024 + n] = acc[mi][ni][r2] + bb + Xf[(size_t)m * 1024 + n];
            }
        }
    }
}

// ---------------- flash attention v2: 8 waves x 32 q, s-half phases, small Ps ----------------
// (byte-identical to round 5/6)
__global__ __launch_bounds__(512, 4) void attn8(const ushortT* __restrict__ Q,
        const ushortT* __restrict__ K, const ushortT* __restrict__ Vg_t,
        const float* __restrict__ mask, ushortT* __restrict__ ctx) {
    __shared__ __align__(16) ushortT Ks[128 * 64];      // 16 KB
    __shared__ __align__(16) ushortT Vt[64 * 128];      // 16 KB
    __shared__ __align__(16) ushortT Ps[8][32 * 36];    // 18 KB

    const int tid = threadIdx.x;
    const int lane = tid & 63;
    const int w = tid >> 6;           // 0..7
    const int qd = lane >> 4;
    const int ln = lane & 15;
    const int l = blockIdx.x;
    const int bh = l & 127;
    const int b = bh >> 4;
    const int h = bh & 15;
    const int qb = l >> 7;

    const ushortT* Qg = Q + (size_t)bh * 65536;
    const ushortT* Kg = K + (size_t)bh * 65536;
    const ushortT* Vg = Vg_t + (size_t)bh * 65536;
    const float* mrow = mask + b * 1024;
    const float LOG2E = 1.4426950408889634f;
    const float SCL = 0.125f * 1.4426950408889634f;   // fold 1/sqrt(64) and log2e

    // resident Q B-fragments: q = qb*256 + w*32 + g*16 + ln
    short8 qf[2][2];
#pragma unroll
    for (int g = 0; g < 2; g++)
#pragma unroll
        for (int ks = 0; ks < 2; ks++)
            qf[g][ks] = *(const short8*)(Qg + (size_t)(qb * 256 + w * 32 + g * 16 + ln) * 64 + ks * 32 + qd * 8);

    float lst[2] = {0.f, 0.f};        // per-lane partial row-sum (qd-reduce deferred)
    floatx4 accO[2][4];
#pragma unroll
    for (int g = 0; g < 2; g++)
#pragma unroll
        for (int j = 0; j < 4; j++) accO[g][j] = (floatx4){0.f, 0.f, 0.f, 0.f};

    // staging lane geometry (8 waves x 2 chunks each)
    const int ksr = lane >> 3;          // K: s-subrow within 8-row group
    const int kc  = lane & 7;           // K: chunk index (8 x 16B per 128B row)
    const int vdr = lane >> 4;          // V: d-subrow within 4-row group
    const int vcc = lane & 15;          // V: chunk index (16 x 16B per 256B row)

    for (int kt = 0; kt < 8; ++kt) {
        __syncthreads();   // all waves done reading Ks/Vt of kt-1

        // stage K tile [128 s][64 d], chunk g2 of row s at slot g2^(s&7)
#pragma unroll
        for (int ii = 0; ii < 2; ii++) {
            int i = w * 2 + ii;
            int srow = i * 8 + ksr;
            gload_lds16(Kg + (size_t)(kt * 128 + srow) * 64 + (kc ^ ksr) * 8,
                        Ks + i * 512 + lane * 8);
        }
        // stage V^T tile [64 d][128 s], chunk g2 of row d at slot g2^(d&15)
#pragma unroll
        for (int ii = 0; ii < 2; ii++) {
            int i = w * 2 + ii;
            int d = i * 4 + vdr;
            gload_lds16(Vg + (size_t)d * 1024 + kt * 128 + (vcc ^ (d & 15)) * 8,
                        Vt + i * 512 + lane * 8);
        }

        __syncthreads();   // tiles ready

#pragma unroll
        for (int h2 = 0; h2 < 2; ++h2) {
#pragma unroll
            for (int mip = 0; mip < 2; ++mip) {
                // ---- QK^T over this 32-s half (S^T frags: col=q=ln, row=s) ----
                floatx4 sv[2][2];
#pragma unroll
                for (int mi2 = 0; mi2 < 2; mi2++)
#pragma unroll
                    for (int g = 0; g < 2; g++) sv[mi2][g] = (floatx4){0.f, 0.f, 0.f, 0.f};
#pragma unroll
                for (int ks = 0; ks < 2; ks++) {
                    short8 af[2];
#pragma unroll
                    for (int mi2 = 0; mi2 < 2; mi2++)
                        af[mi2] = *(const short8*)&Ks[(h2 * 64 + mip * 32 + mi2 * 16 + ln) * 64 +
                                                      (((ks * 4 + qd) ^ (ln & 7)) * 8)];
#pragma unroll
                    for (int mi2 = 0; mi2 < 2; mi2++)
#pragma unroll
                        for (int g = 0; g < 2; g++)
                            sv[mi2][g] = __builtin_amdgcn_mfma_f32_16x16x32_bf16(af[mi2], qf[g][ks], sv[mi2][g], 0, 0, 0);
                }

                // ---- softmax-lite: p = exp2(s*SCL + mask*LOG2E), write Ps half ----
#pragma unroll
                for (int mi2 = 0; mi2 < 2; mi2++) {
                    floatx4 m4 = *(const floatx4*)(mrow + kt * 128 + h2 * 64 + mip * 32 + mi2 * 16 + qd * 4);
                    floatx4 mm;
                    mm[0] = m4[0] * LOG2E; mm[1] = m4[1] * LOG2E;
                    mm[2] = m4[2] * LOG2E; mm[3] = m4[3] * LOG2E;
#pragma unroll
                    for (int g = 0; g < 2; g++) {
                        float p0 = __builtin_amdgcn_exp2f(sv[mi2][g][0] * SCL + mm[0]);
                        float p1 = __builtin_amdgcn_exp2f(sv[mi2][g][1] * SCL + mm[1]);
                        float p2 = __builtin_amdgcn_exp2f(sv[mi2][g][2] * SCL + mm[2]);
                        float p3 = __builtin_amdgcn_exp2f(sv[mi2][g][3] * SCL + mm[3]);
                        lst[g] += (p0 + p1) + (p2 + p3);
                        uint2 wv;
                        wv.x = pack2_trunc(p0, p1);
                        wv.y = pack2_trunc(p2, p3);
                        *(uint2*)&Ps[w][(g * 16 + ln) * 36 + mi2 * 16 + qd * 4] = wv;
                    }
                }

                // ---- PV for k-slice = this s-half (per-wave Ps, no barrier) ----
                short8 ap[2], bv[4];
#pragma unroll
                for (int g = 0; g < 2; g++)
                    ap[g] = *(const short8*)&Ps[w][(g * 16 + ln) * 36 + qd * 8];
#pragma unroll
                for (int j = 0; j < 4; j++)
                    bv[j] = *(const short8*)&Vt[(j * 16 + ln) * 128 +
                                                (((h2 * 8 + mip * 4 + qd) ^ ln) * 8)];
#pragma unroll
                for (int g = 0; g < 2; g++)
#pragma unroll
                    for (int j = 0; j < 4; j++)
                        accO[g][j] = __builtin_amdgcn_mfma_f32_16x16x32_bf16(ap[g], bv[j], accO[g][j], 0, 0, 0);
            }
        }
    }

    // deferred qd-reduction of row sums (linear, so once at the end)
#pragma unroll
    for (int g = 0; g < 2; g++) {
        lst[g] += __shfl_xor(lst[g], 16, 64);
        lst[g] += __shfl_xor(lst[g], 32, 64);
    }

    // epilogue: divide by l (lane transpose once) and store ctx [b][s=q][h*64+d]
#pragma unroll
    for (int g = 0; g < 2; g++) {
#pragma unroll
        for (int r = 0; r < 4; r++) {
            float lv = __shfl(lst[g], qd * 4 + r, 64);
            float linv = 1.f / lv;
            int q = qb * 256 + w * 32 + g * 16 + qd * 4 + r;
#pragma unroll
            for (int j = 0; j < 4; j++) {
                int d = j * 16 + ln;
                ctx[((size_t)(b * 1024 + q)) * 1024 + h * 64 + d] = f2bf(accO[g][j][r] * linv);
            }
        }
    }
}

// ---------------- LayerNorm (residual pre-added by oproj epilogue) ----------------
__global__ __launch_bounds__(256) void ln_res(const float* __restrict__ Pj,
        const float* __restrict__ gamma, const float* __restrict__ beta, float* __restrict__ out) {
    __shared__ float red[8];
    int row = blockIdx.x;
    int t = threadIdx.x;
    const float4 p4 = ((const float4*)(Pj + (size_t)row * 1024))[t];
    float r0 = p4.x, r1 = p4.y, r2 = p4.z, r3 = p4.w;
    float s = r0 + r1 + r2 + r3;
    float ss = r0 * r0 + r1 * r1 + r2 * r2 + r3 * r3;
#pragma unroll
    for (int o = 1; o < 64; o <<= 1) { s += __shfl_xor(s, o, 64); ss += __shfl_xor(ss, o, 64); }
    int w = t >> 6;
    if ((t & 63) == 0) { red[w] = s; red[4 + w] = ss; }
    __syncthreads();
    s = red[0] + red[1] + red[2] + red[3];
    ss = red[4] + red[5] + red[6] + red[7];
    float mu = s * (1.f / 1024.f);
    float var = ss * (1.f / 1024.f) - mu * mu;
    float inv = rsqrtf(var + 1e-12f);
    const float4 g4 = ((const float4*)gamma)[t];
    const float4 b4 = ((const float4*)beta)[t];
    float4 o4;
    o4.x = (r0 - mu) * inv * g4.x + b4.x;
    o4.y = (r1 - mu) * inv * g4.y + b4.y;
    o4.z = (r2 - mu) * inv * g4.z + b4.z;
    o4.w = (r3 - mu) * inv * g4.w + b4.w;
    ((float4*)(out + (size_t)row * 1024))[t] = o4;
}

extern "C" void kernel_launch(void* const* d_in, const int* in_sizes, int n_in,
                              void* d_out, int out_size, void* d_ws, size_t ws_size,
                              hipStream_t stream) {
    const float* x     = (const float*)d_in[0];
    const float* mask  = (const float*)d_in[1];
    const float* Wq    = (const float*)d_in[2];
    const float* bq    = (const float*)d_in[3];
    const float* Wk    = (const float*)d_in[4];
    const float* bk    = (const float*)d_in[5];
    const float* Wv    = (const float*)d_in[6];
    const float* bv    = (const float*)d_in[7];
    const float* Wo    = (const float*)d_in[8];
    const float* bo    = (const float*)d_in[9];
    const float* gamma = (const float*)d_in[10];
    const float* beta  = (const float*)d_in[11];
    float* out = (float*)d_out;

    char* ws = (char*)d_ws;
    ushortT* Xb   = (ushortT*)(ws);
    ushortT* Wall = (ushortT*)(ws + (16u << 20));  // stacked Wq|Wk|Wv [3072][1024], 6 MB
    ushortT* Wob  = (ushortT*)(ws + (22u << 20));
    ushortT* Qb   = (ushortT*)(ws + (24u << 20));
    ushortT* Kb   = (ushortT*)(ws + (40u << 20));
    ushortT* Vb   = (ushortT*)(ws + (56u << 20));  // V^T [bh][d][s]
    ushortT* Cb   = (ushortT*)(ws);                // ctx reuses Xb
    float*   Pj   = (float*)(ws + (24u << 20));    // fp32 proj reuses Q/K

    cvt_all<<<12288, 256, 0, stream>>>(x, Wq, Wk, Wv, Wo, Xb, Wall, Wob);
    qkv_pipe<<<512, 512, 0, stream>>>(Xb, Wall, bq, bk, bv, Qb, Kb, Vb);
    attn8<<<512, 512, 0, stream>>>(Qb, Kb, Vb, mask, Cb);
    oproj_gemm3<<<256, 512, 0, stream>>>(Cb, Wob, bo, x, Pj);
    ln_res<<<8192, 256, 0, stream>>>(Pj, gamma, beta, out);
}

// Round 8
// 264.411 us; speedup vs baseline: 1.0296x; 1.0130x over previous
//
#include <hip/hip_runtime.h>

#define NHh 16

typedef unsigned short ushortT;
typedef __attribute__((ext_vector_type(8))) short short8;
typedef __attribute__((ext_vector_type(4))) float floatx4;

__device__ __forceinline__ ushortT f2bf(float x) {
    union { float f; unsigned int u; } cv; cv.f = x;
    unsigned int u = cv.u;
    unsigned int r = u + 0x7fffu + ((u >> 16) & 1u);
    return (ushortT)(r >> 16);
}

// truncating pack of two fp32 -> packed bf16x2 (cheap; used for P which is in [0,1])
__device__ __forceinline__ unsigned pack2_trunc(float a, float b) {
    union { float f; unsigned u; } ua, ub;
    ua.f = a; ub.f = b;
    return (ub.u & 0xffff0000u) | (ua.u >> 16);
}

__device__ __forceinline__ void gload_lds16(const ushortT* g, ushortT* l) {
    __builtin_amdgcn_global_load_lds(
        (const __attribute__((address_space(1))) void*)g,
        (__attribute__((address_space(3))) void*)l, 16, 0, 0);
}

// ---------------- fp32 -> bf16 converter (X + all weights in one dispatch) ----------------
__global__ __launch_bounds__(256) void cvt_all(const float* __restrict__ x,
        const float* __restrict__ W0, const float* __restrict__ W1,
        const float* __restrict__ W2, const float* __restrict__ W3,
        ushortT* __restrict__ Xb, ushortT* __restrict__ Wall, ushortT* __restrict__ Wob) {
    int bid = blockIdx.x;
    const float* in; ushortT* out; int i;
    if (bid < 8192) {
        in = x; out = Xb; i = bid * 256 + threadIdx.x;
    } else {
        int z = (bid - 8192) >> 10;
        in = (z == 0) ? W0 : (z == 1) ? W1 : (z == 2) ? W2 : W3;
        out = (z < 3) ? (Wall + (size_t)z * 1048576) : Wob;
        i = ((bid - 8192) & 1023) * 256 + threadIdx.x;
    }
    float4 f = ((const float4*)in)[i];
    uint2 o;
    o.x = (unsigned)f2bf(f.x) | ((unsigned)f2bf(f.y) << 16);
    o.y = (unsigned)f2bf(f.z) | ((unsigned)f2bf(f.w) << 16);
    ((uint2*)out)[i] = o;
}

// ======== stacked QKV GEMM: 256x192 tile, 16 waves (4Mx4N), 512 blocks = 2 exact rounds ====
// 1024 threads -> 4 waves/SIMD co-resident: TLP hides ds_read/stage/drain segments.
// Per-wave output 64x48 (acc[4][3] = 48 VGPR); per-ks frag reuse keeps ~100 VGPR total.
// LDS: A 2x32KB + B 2x24KB = 112 KB, st_16x32 swizzle (0-conflict), dbuf.
__global__ __launch_bounds__(1024, 4) void qkv16(
        const ushortT* __restrict__ X, const ushortT* __restrict__ Wall,
        const float* __restrict__ b0, const float* __restrict__ b1, const float* __restrict__ b2,
        ushortT* __restrict__ Qo, ushortT* __restrict__ Ko, ushortT* __restrict__ Vo) {
    __shared__ __align__(16) ushortT As[2 * 16384];   // 64 KB
    __shared__ __align__(16) ushortT Bs[2 * 12288];   // 48 KB

    const int l = blockIdx.x;
    const int xcd = l & 7;
    const int j = l >> 3;             // 0..63
    const int mg = j >> 4;            // 0..3
    const int nt = j & 15;            // 0..15
    const int arow0 = (mg * 8 + xcd) * 256;   // X token-panel grouped per XCD
    const int brow0 = nt * 192;               // stacked out-dim tile

    const int tid = threadIdx.x;
    const int lane = tid & 63;
    const int w = tid >> 6;           // 0..15
    const int wr = w >> 2;            // 0..3 (M)
    const int wc = w & 3;             // 0..3 (N)
    const int qd = lane >> 4, ln = lane & 15;

    // staging addrs: A 2 chunks/thread (32KB), B 1 chunk + tid<512 a 2nd (24KB)
    const ushortT* srcA[2]; int oA[2];
#pragma unroll
    for (int k = 0; k < 2; k++) {
        int o = k * 16384 + tid * 16;
        int rowblk = o >> 11, ks = (o >> 10) & 1, r = (o >> 6) & 15;
        int c2 = ((o >> 4) & 3) ^ ((r >> 3) << 1);
        srcA[k] = X + (size_t)(arow0 + rowblk * 16 + r) * 1024 + ks * 32 + c2 * 8;
        oA[k] = o;
    }
    const ushortT* srcB[2]; int oB[2];
#pragma unroll
    for (int k = 0; k < 2; k++) {
        int o = k * 16384 + tid * 16;         // k=1 valid only for tid<512
        int rowblk = o >> 11, ks = (o >> 10) & 1, r = (o >> 6) & 15;
        int c2 = ((o >> 4) & 3) ^ ((r >> 3) << 1);
        srcB[k] = Wall + (size_t)(brow0 + rowblk * 16 + r) * 1024 + ks * 32 + c2 * 8;
        oB[k] = o;
    }

    floatx4 acc[4][3];
#pragma unroll
    for (int i = 0; i < 4; i++)
#pragma unroll
        for (int jj = 0; jj < 3; jj++) acc[i][jj] = (floatx4){0.f, 0.f, 0.f, 0.f};

    auto STAGE = [&](int buf) {
#pragma unroll
        for (int k = 0; k < 2; k++) {
            gload_lds16(srcA[k], (ushortT*)((char*)As + buf * 32768 + oA[k]));
            srcA[k] += 64;
        }
        gload_lds16(srcB[0], (ushortT*)((char*)Bs + buf * 24576 + oB[0]));
        srcB[0] += 64;
        if (tid < 512) {
            gload_lds16(srcB[1], (ushortT*)((char*)Bs + buf * 24576 + oB[1]));
            srcB[1] += 64;
        }
    };

    const int lnc = ln * 64 + ((qd ^ ((ln >> 3) << 1)) * 16);  // swizzled in-subtile byte off

    STAGE(0);
    asm volatile("s_waitcnt vmcnt(0)" ::: "memory");
    __builtin_amdgcn_s_barrier();

    for (int T = 0; T < 16; T++) {
        const char* Ab = (const char*)As + (T & 1) * 32768;
        const char* Bb = (const char*)Bs + (T & 1) * 24576;
        if (T < 15) STAGE((T + 1) & 1);       // tile T+1 -> other buffer
        short8 af[4], bf[3];
#pragma unroll
        for (int ks = 0; ks < 2; ks++) {
#pragma unroll
            for (int mi = 0; mi < 4; mi++)
                af[mi] = *(const short8*)(Ab + (wr * 4 + mi) * 2048 + ks * 1024 + lnc);
#pragma unroll
            for (int ni = 0; ni < 3; ni++)
                bf[ni] = *(const short8*)(Bb + (wc * 3 + ni) * 2048 + ks * 1024 + lnc);
            asm volatile("s_waitcnt lgkmcnt(0)" ::: "memory");
            __builtin_amdgcn_sched_barrier(0);
            __builtin_amdgcn_s_setprio(1);
#pragma unroll
            for (int mi = 0; mi < 4; mi++)
#pragma unroll
                for (int ni = 0; ni < 3; ni++)
                    acc[mi][ni] = __builtin_amdgcn_mfma_f32_16x16x32_bf16(af[mi], bf[ni], acc[mi][ni], 0, 0, 0);
            __builtin_amdgcn_s_setprio(0);
        }
        asm volatile("s_waitcnt vmcnt(0)" ::: "memory");   // tile T+1 landed (issued pre-compute)
        __builtin_amdgcn_s_barrier();                      // all waves done reading buf[T&1]
    }

    // epilogue (structure verified rounds 4-7; wave map 4Mx4N)
#pragma unroll
    for (int ni = 0; ni < 3; ni++) {
        int n = brow0 + wc * 48 + ni * 16 + ln;   // stacked out dim 0..3071
        int z = n >> 10;
        int col = n & 1023;
        int h = col >> 6, d = col & 63;
        const float* bias = (z == 0) ? b0 : (z == 1) ? b1 : b2;
        float bb = bias[col];
        if (z == 2) {
#pragma unroll
            for (int mi = 0; mi < 4; mi++) {
                int m = arow0 + wr * 64 + mi * 16 + qd * 4;   // token (4-aligned)
                int b = m >> 10, s = m & 1023;
                ushort4 pk;
                pk.x = f2bf(acc[mi][ni][0] + bb);
                pk.y = f2bf(acc[mi][ni][1] + bb);
                pk.z = f2bf(acc[mi][ni][2] + bb);
                pk.w = f2bf(acc[mi][ni][3] + bb);
                *(ushort4*)&Vo[((size_t)(b * NHh + h) * 64 + d) * 1024 + s] = pk;
            }
        } else {
            ushortT* Out = z ? Ko : Qo;
#pragma unroll
            for (int mi = 0; mi < 4; mi++) {
#pragma unroll
                for (int r2 = 0; r2 < 4; r2++) {
                    int m = arow0 + wr * 64 + mi * 16 + qd * 4 + r2;  // token
                    int b = m >> 10, s = m & 1023;
                    Out[(size_t)((b * NHh + h) * 1024 + s) * 64 + d] =
                        f2bf(acc[mi][ni][r2] + bb);
                }
            }
        }
    }
}

// ======== out-proj GEMM: 256x128 tile, 16 waves (4Mx4N), 256 blocks = 1 exact round ========
// Residual (+X) fused into the epilogue; Pj = ctx*Wo^T + bo + X.
__global__ __launch_bounds__(1024, 4) void oproj16(const ushortT* __restrict__ A,
        const ushortT* __restrict__ Wt, const float* __restrict__ bias,
        const float* __restrict__ Xf, float* __restrict__ Pj) {
    __shared__ __align__(16) ushortT As[2 * 16384];   // 64 KB
    __shared__ __align__(16) ushortT Bs[2 * 8192];    // 32 KB

    const int l = blockIdx.x;
    const int xcd = l & 7;
    const int j = l >> 3;             // 0..31
    const int tid = threadIdx.x;
    const int lane = tid & 63;
    const int w = tid >> 6;           // 0..15
    const int wr = w >> 2, wc = w & 3;
    const int qd = lane >> 4, ln = lane & 15;

    const int arow0 = ((j & 3) * 8 + xcd) * 256;  // ctx token-panel per XCD
    const int brow0 = (j >> 2) * 128;             // Wo out-dim tile

    const ushortT* srcA[2]; int oA[2];
#pragma unroll
    for (int k = 0; k < 2; k++) {
        int o = k * 16384 + tid * 16;
        int rowblk = o >> 11, ks = (o >> 10) & 1, r = (o >> 6) & 15;
        int c2 = ((o >> 4) & 3) ^ ((r >> 3) << 1);
        srcA[k] = A + (size_t)(arow0 + rowblk * 16 + r) * 1024 + ks * 32 + c2 * 8;
        oA[k] = o;
    }
    const ushortT* srcB0; int oB0;
    {
        int o = tid * 16;
        int rowblk = o >> 11, ks = (o >> 10) & 1, r = (o >> 6) & 15;
        int c2 = ((o >> 4) & 3) ^ ((r >> 3) << 1);
        srcB0 = Wt + (size_t)(brow0 + rowblk * 16 + r) * 1024 + ks * 32 + c2 * 8;
        oB0 = o;
    }

    floatx4 acc[4][2];
#pragma unroll
    for (int i = 0; i < 4; i++)
#pragma unroll
        for (int jj = 0; jj < 2; jj++) acc[i][jj] = (floatx4){0.f, 0.f, 0.f, 0.f};

    auto STAGE = [&](int buf) {
#pragma unroll
        for (int k = 0; k < 2; k++) {
            gload_lds16(srcA[k], (ushortT*)((char*)As + buf * 32768 + oA[k]));
            srcA[k] += 64;
        }
        gload_lds16(srcB0, (ushortT*)((char*)Bs + buf * 16384 + oB0));
        srcB0 += 64;
    };

    const int lnc = ln * 64 + ((qd ^ ((ln >> 3) << 1)) * 16);

    STAGE(0);
    asm volatile("s_waitcnt vmcnt(0)" ::: "memory");
    __builtin_amdgcn_s_barrier();

    for (int T = 0; T < 16; T++) {
        const char* Ab = (const char*)As + (T & 1) * 32768;
        const char* Bb = (const char*)Bs + (T & 1) * 16384;
        if (T < 15) STAGE((T + 1) & 1);
        short8 af[4], bf[2];
#pragma unroll
        for (int ks = 0; ks < 2; ks++) {
#pragma unroll
            for (int mi = 0; mi < 4; mi++)
                af[mi] = *(const short8*)(Ab + (wr * 4 + mi) * 2048 + ks * 1024 + lnc);
#pragma unroll
            for (int ni = 0; ni < 2; ni++)
                bf[ni] = *(const short8*)(Bb + (wc * 2 + ni) * 2048 + ks * 1024 + lnc);
            asm volatile("s_waitcnt lgkmcnt(0)" ::: "memory");
            __builtin_amdgcn_sched_barrier(0);
            __builtin_amdgcn_s_setprio(1);
#pragma unroll
            for (int mi = 0; mi < 4; mi++)
#pragma unroll
                for (int ni = 0; ni < 2; ni++)
                    acc[mi][ni] = __builtin_amdgcn_mfma_f32_16x16x32_bf16(af[mi], bf[ni], acc[mi][ni], 0, 0, 0);
            __builtin_amdgcn_s_setprio(0);
        }
        asm volatile("s_waitcnt vmcnt(0)" ::: "memory");
        __builtin_amdgcn_s_barrier();
    }

#pragma unroll
    for (int ni = 0; ni < 2; ni++) {
        int n = brow0 + wc * 32 + ni * 16 + ln;
        float bb = bias[n];
#pragma unroll
        for (int mi = 0; mi < 4; mi++) {
#pragma unroll
            for (int r2 = 0; r2 < 4; r2++) {
                int m = arow0 + wr * 64 + mi * 16 + qd * 4 + r2;
                Pj[(size_t)m * 1024 + n] = acc[mi][ni][r2] + bb + Xf[(size_t)m * 1024 + n];
            }
        }
    }
}

// ---------------- flash attention v2: 8 waves x 32 q, s-half phases, small Ps ----------------
// (byte-identical to rounds 5-7)
__global__ __launch_bounds__(512, 4) void attn8(const ushortT* __restrict__ Q,
        const ushortT* __restrict__ K, const ushortT* __restrict__ Vg_t,
        const float* __restrict__ mask, ushortT* __restrict__ ctx) {
    __shared__ __align__(16) ushortT Ks[128 * 64];      // 16 KB
    __shared__ __align__(16) ushortT Vt[64 * 128];      // 16 KB
    __shared__ __align__(16) ushortT Ps[8][32 * 36];    // 18 KB

    const int tid = threadIdx.x;
    const int lane = tid & 63;
    const int w = tid >> 6;           // 0..7
    const int qd = lane >> 4;
    const int ln = lane & 15;
    const int l = blockIdx.x;
    const int bh = l & 127;
    const int b = bh >> 4;
    const int h = bh & 15;
    const int qb = l >> 7;

    const ushortT* Qg = Q + (size_t)bh * 65536;
    const ushortT* Kg = K + (size_t)bh * 65536;
    const ushortT* Vg = Vg_t + (size_t)bh * 65536;
    const float* mrow = mask + b * 1024;
    const float LOG2E = 1.4426950408889634f;
    const float SCL = 0.125f * 1.4426950408889634f;   // fold 1/sqrt(64) and log2e

    // resident Q B-fragments: q = qb*256 + w*32 + g*16 + ln
    short8 qf[2][2];
#pragma unroll
    for (int g = 0; g < 2; g++)
#pragma unroll
        for (int ks = 0; ks < 2; ks++)
            qf[g][ks] = *(const short8*)(Qg + (size_t)(qb * 256 + w * 32 + g * 16 + ln) * 64 + ks * 32 + qd * 8);

    float lst[2] = {0.f, 0.f};        // per-lane partial row-sum (qd-reduce deferred)
    floatx4 accO[2][4];
#pragma unroll
    for (int g = 0; g < 2; g++)
#pragma unroll
        for (int j = 0; j < 4; j++) accO[g][j] = (floatx4){0.f, 0.f, 0.f, 0.f};

    // staging lane geometry (8 waves x 2 chunks each)
    const int ksr = lane >> 3;          // K: s-subrow within 8-row group
    const int kc  = lane & 7;           // K: chunk index (8 x 16B per 128B row)
    const int vdr = lane >> 4;          // V: d-subrow within 4-row group
    const int vcc = lane & 15;          // V: chunk index (16 x 16B per 256B row)

    for (int kt = 0; kt < 8; ++kt) {
        __syncthreads();   // all waves done reading Ks/Vt of kt-1

        // stage K tile [128 s][64 d], chunk g2 of row s at slot g2^(s&7)
#pragma unroll
        for (int ii = 0; ii < 2; ii++) {
            int i = w * 2 + ii;
            int srow = i * 8 + ksr;
            gload_lds16(Kg + (size_t)(kt * 128 + srow) * 64 + (kc ^ ksr) * 8,
                        Ks + i * 512 + lane * 8);
        }
        // stage V^T tile [64 d][128 s], chunk g2 of row d at slot g2^(d&15)
#pragma unroll
        for (int ii = 0; ii < 2; ii++) {
            int i = w * 2 + ii;
            int d = i * 4 + vdr;
            gload_lds16(Vg + (size_t)d * 1024 + kt * 128 + (vcc ^ (d & 15)) * 8,
                        Vt + i * 512 + lane * 8);
        }

        __syncthreads();   // tiles ready

#pragma unroll
        for (int h2 = 0; h2 < 2; ++h2) {
#pragma unroll
            for (int mip = 0; mip < 2; ++mip) {
                // ---- QK^T over this 32-s half (S^T frags: col=q=ln, row=s) ----
                floatx4 sv[2][2];
#pragma unroll
                for (int mi2 = 0; mi2 < 2; mi2++)
#pragma unroll
                    for (int g = 0; g < 2; g++) sv[mi2][g] = (floatx4){0.f, 0.f, 0.f, 0.f};
#pragma unroll
                for (int ks = 0; ks < 2; ks++) {
                    short8 af[2];
#pragma unroll
                    for (int mi2 = 0; mi2 < 2; mi2++)
                        af[mi2] = *(const short8*)&Ks[(h2 * 64 + mip * 32 + mi2 * 16 + ln) * 64 +
                                                      (((ks * 4 + qd) ^ (ln & 7)) * 8)];
#pragma unroll
                    for (int mi2 = 0; mi2 < 2; mi2++)
#pragma unroll
                        for (int g = 0; g < 2; g++)
                            sv[mi2][g] = __builtin_amdgcn_mfma_f32_16x16x32_bf16(af[mi2], qf[g][ks], sv[mi2][g], 0, 0, 0);
                }

                // ---- softmax-lite: p = exp2(s*SCL + mask*LOG2E), write Ps half ----
#pragma unroll
                for (int mi2 = 0; mi2 < 2; mi2++) {
                    floatx4 m4 = *(const floatx4*)(mrow + kt * 128 + h2 * 64 + mip * 32 + mi2 * 16 + qd * 4);
                    floatx4 mm;
                    mm[0] = m4[0] * LOG2E; mm[1] = m4[1] * LOG2E;
                    mm[2] = m4[2] * LOG2E; mm[3] = m4[3] * LOG2E;
#pragma unroll
                    for (int g = 0; g < 2; g++) {
                        float p0 = __builtin_amdgcn_exp2f(sv[mi2][g][0] * SCL + mm[0]);
                        float p1 = __builtin_amdgcn_exp2f(sv[mi2][g][1] * SCL + mm[1]);
                        float p2 = __builtin_amdgcn_exp2f(sv[mi2][g][2] * SCL + mm[2]);
                        float p3 = __builtin_amdgcn_exp2f(sv[mi2][g][3] * SCL + mm[3]);
                        lst[g] += (p0 + p1) + (p2 + p3);
                        uint2 wv;
                        wv.x = pack2_trunc(p0, p1);
                        wv.y = pack2_trunc(p2, p3);
                        *(uint2*)&Ps[w][(g * 16 + ln) * 36 + mi2 * 16 + qd * 4] = wv;
                    }
                }

                // ---- PV for k-slice = this s-half (per-wave Ps, no barrier) ----
                short8 ap[2], bv[4];
#pragma unroll
                for (int g = 0; g < 2; g++)
                    ap[g] = *(const short8*)&Ps[w][(g * 16 + ln) * 36 + qd * 8];
#pragma unroll
                for (int j = 0; j < 4; j++)
                    bv[j] = *(const short8*)&Vt[(j * 16 + ln) * 128 +
                                                (((h2 * 8 + mip * 4 + qd) ^ ln) * 8)];
#pragma unroll
                for (int g = 0; g < 2; g++)
#pragma unroll
                    for (int j = 0; j < 4; j++)
                        accO[g][j] = __builtin_amdgcn_mfma_f32_16x16x32_bf16(ap[g], bv[j], accO[g][j], 0, 0, 0);
            }
        }
    }

    // deferred qd-reduction of row sums (linear, so once at the end)
#pragma unroll
    for (int g = 0; g < 2; g++) {
        lst[g] += __shfl_xor(lst[g], 16, 64);
        lst[g] += __shfl_xor(lst[g], 32, 64);
    }

    // epilogue: divide by l (lane transpose once) and store ctx [b][s=q][h*64+d]
#pragma unroll
    for (int g = 0; g < 2; g++) {
#pragma unroll
        for (int r = 0; r < 4; r++) {
            float lv = __shfl(lst[g], qd * 4 + r, 64);
            float linv = 1.f / lv;
            int q = qb * 256 + w * 32 + g * 16 + qd * 4 + r;
#pragma unroll
            for (int j = 0; j < 4; j++) {
                int d = j * 16 + ln;
                ctx[((size_t)(b * 1024 + q)) * 1024 + h * 64 + d] = f2bf(accO[g][j][r] * linv);
            }
        }
    }
}

// ---------------- LayerNorm (residual pre-added by oproj epilogue) ----------------
__global__ __launch_bounds__(256) void ln_res(const float* __restrict__ Pj,
        const float* __restrict__ gamma, const float* __restrict__ beta, float* __restrict__ out) {
    __shared__ float red[8];
    int row = blockIdx.x;
    int t = threadIdx.x;
    const float4 p4 = ((const float4*)(Pj + (size_t)row * 1024))[t];
    float r0 = p4.x, r1 = p4.y, r2 = p4.z, r3 = p4.w;
    float s = r0 + r1 + r2 + r3;
    float ss = r0 * r0 + r1 * r1 + r2 * r2 + r3 * r3;
#pragma unroll
    for (int o = 1; o < 64; o <<= 1) { s += __shfl_xor(s, o, 64); ss += __shfl_xor(ss, o, 64); }
    int w = t >> 6;
    if ((t & 63) == 0) { red[w] = s; red[4 + w] = ss; }
    __syncthreads();
    s = red[0] + red[1] + red[2] + red[3];
    ss = red[4] + red[5] + red[6] + red[7];
    float mu = s * (1.f / 1024.f);
    float var = ss * (1.f / 1024.f) - mu * mu;
    float inv = rsqrtf(var + 1e-12f);
    const float4 g4 = ((const float4*)gamma)[t];
    const float4 b4 = ((const float4*)beta)[t];
    float4 o4;
    o4.x = (r0 - mu) * inv * g4.x + b4.x;
    o4.y = (r1 - mu) * inv * g4.y + b4.y;
    o4.z = (r2 - mu) * inv * g4.z + b4.z;
    o4.w = (r3 - mu) * inv * g4.w + b4.w;
    ((float4*)(out + (size_t)row * 1024))[t] = o4;
}

extern "C" void kernel_launch(void* const* d_in, const int* in_sizes, int n_in,
                              void* d_out, int out_size, void* d_ws, size_t ws_size,
                              hipStream_t stream) {
    const float* x     = (const float*)d_in[0];
    const float* mask  = (const float*)d_in[1];
    const float* Wq    = (const float*)d_in[2];
    const float* bq    = (const float*)d_in[3];
    const float* Wk    = (const float*)d_in[4];
    const float* bk    = (const float*)d_in[5];
    const float* Wv    = (const float*)d_in[6];
    const float* bv    = (const float*)d_in[7];
    const float* Wo    = (const float*)d_in[8];
    const float* bo    = (const float*)d_in[9];
    const float* gamma = (const float*)d_in[10];
    const float* beta  = (const float*)d_in[11];
    float* out = (float*)d_out;

    char* ws = (char*)d_ws;
    ushortT* Xb   = (ushortT*)(ws);
    ushortT* Wall = (ushortT*)(ws + (16u << 20));  // stacked Wq|Wk|Wv [3072][1024], 6 MB
    ushortT* Wob  = (ushortT*)(ws + (22u << 20));
    ushortT* Qb   = (ushortT*)(ws + (24u << 20));
    ushortT* Kb   = (ushortT*)(ws + (40u << 20));
    ushortT* Vb   = (ushortT*)(ws + (56u << 20));  // V^T [bh][d][s]
    ushortT* Cb   = (ushortT*)(ws);                // ctx reuses Xb
    float*   Pj   = (float*)(ws + (24u << 20));    // fp32 proj reuses Q/K

    cvt_all<<<12288, 256, 0, stream>>>(x, Wq, Wk, Wv, Wo, Xb, Wall, Wob);
    qkv16<<<512, 1024, 0, stream>>>(Xb, Wall, bq, bk, bv, Qb, Kb, Vb);
    attn8<<<512, 512, 0, stream>>>(Qb, Kb, Vb, mask, Cb);
    oproj16<<<256, 1024, 0, stream>>>(Cb, Wob, bo, x, Pj);
    ln_res<<<8192, 256, 0, stream>>>(Pj, gamma, beta, out);
}

// Round 10
// 259.021 us; speedup vs baseline: 1.0510x; 1.0208x over previous
//
#include <hip/hip_runtime.h>

#define NHh 16

typedef unsigned short ushortT;
typedef __attribute__((ext_vector_type(8))) short short8;
typedef __attribute__((ext_vector_type(4))) float floatx4;

__device__ __forceinline__ ushortT f2bf(float x) {
    union { float f; unsigned int u; } cv; cv.f = x;
    unsigned int u = cv.u;
    unsigned int r = u + 0x7fffu + ((u >> 16) & 1u);
    return (ushortT)(r >> 16);
}

// truncating pack of two fp32 -> packed bf16x2 (cheap; used for P which is in [0,1])
__device__ __forceinline__ unsigned pack2_trunc(float a, float b) {
    union { float f; unsigned u; } ua, ub;
    ua.f = a; ub.f = b;
    return (ub.u & 0xffff0000u) | (ua.u >> 16);
}

__device__ __forceinline__ void gload_lds16(const ushortT* g, ushortT* l) {
    __builtin_amdgcn_global_load_lds(
        (const __attribute__((address_space(1))) void*)g,
        (__attribute__((address_space(3))) void*)l, 16, 0, 0);
}

// ---------------- fp32 -> bf16 converter (X + all weights in one dispatch) ----------------
__global__ __launch_bounds__(256) void cvt_all(const float* __restrict__ x,
        const float* __restrict__ W0, const float* __restrict__ W1,
        const float* __restrict__ W2, const float* __restrict__ W3,
        ushortT* __restrict__ Xb, ushortT* __restrict__ Wall, ushortT* __restrict__ Wob) {
    int bid = blockIdx.x;
    const float* in; ushortT* out; int i;
    if (bid < 8192) {
        in = x; out = Xb; i = bid * 256 + threadIdx.x;
    } else {
        int z = (bid - 8192) >> 10;
        in = (z == 0) ? W0 : (z == 1) ? W1 : (z == 2) ? W2 : W3;
        out = (z < 3) ? (Wall + (size_t)z * 1048576) : Wob;
        i = ((bid - 8192) & 1023) * 256 + threadIdx.x;
    }
    float4 f = ((const float4*)in)[i];
    uint2 o;
    o.x = (unsigned)f2bf(f.x) | ((unsigned)f2bf(f.y) << 16);
    o.y = (unsigned)f2bf(f.z) | ((unsigned)f2bf(f.w) << 16);
    ((uint2*)out)[i] = o;
}

// ======== stacked QKV GEMM: 256x192, 16 waves (4Mx4N), r6-pipeline, 512 blocks ========
// Per tile T (u0/u1, r6-verified schedule at the r8-verified 4-waves/SIMD geometry):
//  u0: RD(T,ks1)->a1 | MFMA(T,ks0) on a0 | lgkm(0) | vmcnt(0) | barrier
//  u1: STAGE(T+2)->buf[T&1] (frags of T all in regs -> overwrite legal) |
//      RD(T+1,ks0)->a0 | MFMA(T,ks1) on a1 | lgkm(0)
// acc lives in AGPRs (r8: VGPR_Count=56), so 14 live frags fit under the 128-VGPR cap.
__global__ __launch_bounds__(1024, 4) void qkv16(
        const ushortT* __restrict__ X, const ushortT* __restrict__ Wall,
        const float* __restrict__ b0, const float* __restrict__ b1, const float* __restrict__ b2,
        ushortT* __restrict__ Qo, ushortT* __restrict__ Ko, ushortT* __restrict__ Vo) {
    __shared__ __align__(16) ushortT As[2 * 16384];   // 64 KB
    __shared__ __align__(16) ushortT Bs[2 * 12288];   // 48 KB

    const int l = blockIdx.x;
    const int xcd = l & 7;
    const int j = l >> 3;             // 0..63
    const int mg = j >> 4;            // 0..3
    const int nt = j & 15;            // 0..15
    const int arow0 = (mg * 8 + xcd) * 256;   // X token-panel grouped per XCD
    const int brow0 = nt * 192;               // stacked out-dim tile

    const int tid = threadIdx.x;
    const int lane = tid & 63;
    const int w = tid >> 6;           // 0..15
    const int wr = w >> 2;            // 0..3 (M)
    const int wc = w & 3;             // 0..3 (N)
    const int qd = lane >> 4, ln = lane & 15;

    // staging addrs: A 2 chunks/thread (32KB), B 1 chunk + tid<512 a 2nd (24KB)
    const ushortT* srcA[2]; int oA[2];
#pragma unroll
    for (int k = 0; k < 2; k++) {
        int o = k * 16384 + tid * 16;
        int rowblk = o >> 11, ks = (o >> 10) & 1, r = (o >> 6) & 15;
        int c2 = ((o >> 4) & 3) ^ ((r >> 3) << 1);
        srcA[k] = X + (size_t)(arow0 + rowblk * 16 + r) * 1024 + ks * 32 + c2 * 8;
        oA[k] = o;
    }
    const ushortT* srcB[2]; int oB[2];
#pragma unroll
    for (int k = 0; k < 2; k++) {
        int o = k * 16384 + tid * 16;         // k=1 valid only for tid<512
        int rowblk = o >> 11, ks = (o >> 10) & 1, r = (o >> 6) & 15;
        int c2 = ((o >> 4) & 3) ^ ((r >> 3) << 1);
        srcB[k] = Wall + (size_t)(brow0 + rowblk * 16 + r) * 1024 + ks * 32 + c2 * 8;
        oB[k] = o;
    }

    floatx4 acc[4][3];
#pragma unroll
    for (int i = 0; i < 4; i++)
#pragma unroll
        for (int jj = 0; jj < 3; jj++) acc[i][jj] = (floatx4){0.f, 0.f, 0.f, 0.f};

    auto STAGE = [&](int buf) {
#pragma unroll
        for (int k = 0; k < 2; k++) {
            gload_lds16(srcA[k], (ushortT*)((char*)As + buf * 32768 + oA[k]));
            srcA[k] += 64;
        }
        gload_lds16(srcB[0], (ushortT*)((char*)Bs + buf * 24576 + oB[0]));
        srcB[0] += 64;
        if (tid < 512) {
            gload_lds16(srcB[1], (ushortT*)((char*)Bs + buf * 24576 + oB[1]));
            srcB[1] += 64;
        }
    };

    const int lnc = ln * 64 + ((qd ^ ((ln >> 3) << 1)) * 16);  // swizzled in-subtile byte off

    short8 a0[4], bf0[3], a1[4], bf1[3];   // ping-pong frag sets (static names)

    auto RD = [&](short8 (&af)[4], short8 (&bf)[3], const char* Ab, const char* Bb, int ksb) {
#pragma unroll
        for (int mi = 0; mi < 4; mi++)
            af[mi] = *(const short8*)(Ab + (wr * 4 + mi) * 2048 + ksb + lnc);
#pragma unroll
        for (int ni = 0; ni < 3; ni++)
            bf[ni] = *(const short8*)(Bb + (wc * 3 + ni) * 2048 + ksb + lnc);
    };
    auto MM = [&](short8 (&af)[4], short8 (&bf)[3]) {
        __builtin_amdgcn_s_setprio(1);
#pragma unroll
        for (int mi = 0; mi < 4; mi++)
#pragma unroll
            for (int ni = 0; ni < 3; ni++)
                acc[mi][ni] = __builtin_amdgcn_mfma_f32_16x16x32_bf16(af[mi], bf[ni], acc[mi][ni], 0, 0, 0);
        __builtin_amdgcn_s_setprio(0);
    };

    // prologue: tiles 0,1 staged; tile0 landed (vmcnt(3): >=3 outstanding = tile1's);
    STAGE(0); STAGE(1);
    asm volatile("s_waitcnt vmcnt(3)" ::: "memory");
    __builtin_amdgcn_s_barrier();
    RD(a0, bf0, (const char*)As, (const char*)Bs, 0);
    asm volatile("s_waitcnt lgkmcnt(0)" ::: "memory");
    __builtin_amdgcn_sched_barrier(0);

    for (int T = 0; T < 16; T++) {
        const char* Ab = (const char*)As + (T & 1) * 32768;
        const char* Bb = (const char*)Bs + (T & 1) * 24576;
        const char* An = (const char*)As + ((T + 1) & 1) * 32768;
        const char* Bn = (const char*)Bs + ((T + 1) & 1) * 24576;
        // ---- u0 ----
        RD(a1, bf1, Ab, Bb, 1024);               // frags(T,ks1)
        __builtin_amdgcn_sched_barrier(0);
        MM(a0, bf0);                             // MFMA(T,ks0)
        asm volatile("s_waitcnt lgkmcnt(0)" ::: "memory");   // (T,ks1) in regs; Ab reads done
        asm volatile("s_waitcnt vmcnt(0)" ::: "memory");     // tile T+1 landed (issued last iter)
        __builtin_amdgcn_sched_barrier(0);
        __builtin_amdgcn_s_barrier();            // all waves done reading buf[T&1]
        // ---- u1 ----
        if (T < 14) STAGE(T & 1);                // tile T+2 -> buf[T&1] (now safe)
        if (T < 15) RD(a0, bf0, An, Bn, 0);      // frags(T+1,ks0)
        __builtin_amdgcn_sched_barrier(0);
        MM(a1, bf1);                             // MFMA(T,ks1)
        asm volatile("s_waitcnt lgkmcnt(0)" ::: "memory");
        __builtin_amdgcn_sched_barrier(0);
    }

    // epilogue (structure verified rounds 4-8; wave map 4Mx4N)
#pragma unroll
    for (int ni = 0; ni < 3; ni++) {
        int n = brow0 + wc * 48 + ni * 16 + ln;   // stacked out dim 0..3071
        int z = n >> 10;
        int col = n & 1023;
        int h = col >> 6, d = col & 63;
        const float* bias = (z == 0) ? b0 : (z == 1) ? b1 : b2;
        float bb = bias[col];
        if (z == 2) {
#pragma unroll
            for (int mi = 0; mi < 4; mi++) {
                int m = arow0 + wr * 64 + mi * 16 + qd * 4;   // token (4-aligned)
                int b = m >> 10, s = m & 1023;
                ushort4 pk;
                pk.x = f2bf(acc[mi][ni][0] + bb);
                pk.y = f2bf(acc[mi][ni][1] + bb);
                pk.z = f2bf(acc[mi][ni][2] + bb);
                pk.w = f2bf(acc[mi][ni][3] + bb);
                *(ushort4*)&Vo[((size_t)(b * NHh + h) * 64 + d) * 1024 + s] = pk;
            }
        } else {
            ushortT* Out = z ? Ko : Qo;
#pragma unroll
            for (int mi = 0; mi < 4; mi++) {
#pragma unroll
                for (int r2 = 0; r2 < 4; r2++) {
                    int m = arow0 + wr * 64 + mi * 16 + qd * 4 + r2;  // token
                    int b = m >> 10, s = m & 1023;
                    Out[(size_t)((b * NHh + h) * 1024 + s) * 64 + d] =
                        f2bf(acc[mi][ni][r2] + bb);
                }
            }
        }
    }
}

// ======== out-proj GEMM: 256x128, 16 waves (4Mx4N), r6-pipeline, 256 blocks ========
// Residual (+X) fused into the epilogue; Pj = ctx*Wo^T + bo + X.
__global__ __launch_bounds__(1024, 4) void oproj16(const ushortT* __restrict__ A,
        const ushortT* __restrict__ Wt, const float* __restrict__ bias,
        const float* __restrict__ Xf, float* __restrict__ Pj) {
    __shared__ __align__(16) ushortT As[2 * 16384];   // 64 KB
    __shared__ __align__(16) ushortT Bs[2 * 8192];    // 32 KB

    const int l = blockIdx.x;
    const int xcd = l & 7;
    const int j = l >> 3;             // 0..31
    const int tid = threadIdx.x;
    const int lane = tid & 63;
    const int w = tid >> 6;           // 0..15
    const int wr = w >> 2, wc = w & 3;
    const int qd = lane >> 4, ln = lane & 15;

    const int arow0 = ((j & 3) * 8 + xcd) * 256;  // ctx token-panel per XCD
    const int brow0 = (j >> 2) * 128;             // Wo out-dim tile

    const ushortT* srcA[2]; int oA[2];
#pragma unroll
    for (int k = 0; k < 2; k++) {
        int o = k * 16384 + tid * 16;
        int rowblk = o >> 11, ks = (o >> 10) & 1, r = (o >> 6) & 15;
        int c2 = ((o >> 4) & 3) ^ ((r >> 3) << 1);
        srcA[k] = A + (size_t)(arow0 + rowblk * 16 + r) * 1024 + ks * 32 + c2 * 8;
        oA[k] = o;
    }
    const ushortT* srcB0; int oB0;
    {
        int o = tid * 16;
        int rowblk = o >> 11, ks = (o >> 10) & 1, r = (o >> 6) & 15;
        int c2 = ((o >> 4) & 3) ^ ((r >> 3) << 1);
        srcB0 = Wt + (size_t)(brow0 + rowblk * 16 + r) * 1024 + ks * 32 + c2 * 8;
        oB0 = o;
    }

    floatx4 acc[4][2];
#pragma unroll
    for (int i = 0; i < 4; i++)
#pragma unroll
        for (int jj = 0; jj < 2; jj++) acc[i][jj] = (floatx4){0.f, 0.f, 0.f, 0.f};

    auto STAGE = [&](int buf) {
#pragma unroll
        for (int k = 0; k < 2; k++) {
            gload_lds16(srcA[k], (ushortT*)((char*)As + buf * 32768 + oA[k]));
            srcA[k] += 64;
        }
        gload_lds16(srcB0, (ushortT*)((char*)Bs + buf * 16384 + oB0));
        srcB0 += 64;
    };

    const int lnc = ln * 64 + ((qd ^ ((ln >> 3) << 1)) * 16);

    short8 a0[4], bf0[2], a1[4], bf1[2];

    auto RD = [&](short8 (&af)[4], short8 (&bf)[2], const char* Ab, const char* Bb, int ksb) {
#pragma unroll
        for (int mi = 0; mi < 4; mi++)
            af[mi] = *(const short8*)(Ab + (wr * 4 + mi) * 2048 + ksb + lnc);
#pragma unroll
        for (int ni = 0; ni < 2; ni++)
            bf[ni] = *(const short8*)(Bb + (wc * 2 + ni) * 2048 + ksb + lnc);
    };
    auto MM = [&](short8 (&af)[4], short8 (&bf)[2]) {
        __builtin_amdgcn_s_setprio(1);
#pragma unroll
        for (int mi = 0; mi < 4; mi++)
#pragma unroll
            for (int ni = 0; ni < 2; ni++)
                acc[mi][ni] = __builtin_amdgcn_mfma_f32_16x16x32_bf16(af[mi], bf[ni], acc[mi][ni], 0, 0, 0);
        __builtin_amdgcn_s_setprio(0);
    };

    STAGE(0); STAGE(1);
    asm volatile("s_waitcnt vmcnt(3)" ::: "memory");
    __builtin_amdgcn_s_barrier();
    RD(a0, bf0, (const char*)As, (const char*)Bs, 0);
    asm volatile("s_waitcnt lgkmcnt(0)" ::: "memory");
    __builtin_amdgcn_sched_barrier(0);

    for (int T = 0; T < 16; T++) {
        const char* Ab = (const char*)As + (T & 1) * 32768;
        const char* Bb = (const char*)Bs + (T & 1) * 16384;
        const char* An = (const char*)As + ((T + 1) & 1) * 32768;
        const char* Bn = (const char*)Bs + ((T + 1) & 1) * 16384;
        // u0
        RD(a1, bf1, Ab, Bb, 1024);
        __builtin_amdgcn_sched_barrier(0);
        MM(a0, bf0);
        asm volatile("s_waitcnt lgkmcnt(0)" ::: "memory");
        asm volatile("s_waitcnt vmcnt(0)" ::: "memory");
        __builtin_amdgcn_sched_barrier(0);
        __builtin_amdgcn_s_barrier();
        // u1
        if (T < 14) STAGE(T & 1);
        if (T < 15) RD(a0, bf0, An, Bn, 0);
        __builtin_amdgcn_sched_barrier(0);
        MM(a1, bf1);
        asm volatile("s_waitcnt lgkmcnt(0)" ::: "memory");
        __builtin_amdgcn_sched_barrier(0);
    }

#pragma unroll
    for (int ni = 0; ni < 2; ni++) {
        int n = brow0 + wc * 32 + ni * 16 + ln;
        float bb = bias[n];
#pragma unroll
        for (int mi = 0; mi < 4; mi++) {
#pragma unroll
            for (int r2 = 0; r2 < 4; r2++) {
                int m = arow0 + wr * 64 + mi * 16 + qd * 4 + r2;
                Pj[(size_t)m * 1024 + n] = acc[mi][ni][r2] + bb + Xf[(size_t)m * 1024 + n];
            }
        }
    }
}

// ---------------- flash attention v2: 8 waves x 32 q, s-half phases, small Ps ----------------
// (byte-identical to rounds 5-8)
__global__ __launch_bounds__(512, 4) void attn8(const ushortT* __restrict__ Q,
        const ushortT* __restrict__ K, const ushortT* __restrict__ Vg_t,
        const float* __restrict__ mask, ushortT* __restrict__ ctx) {
    __shared__ __align__(16) ushortT Ks[128 * 64];      // 16 KB
    __shared__ __align__(16) ushortT Vt[64 * 128];      // 16 KB
    __shared__ __align__(16) ushortT Ps[8][32 * 36];    // 18 KB

    const int tid = threadIdx.x;
    const int lane = tid & 63;
    const int w = tid >> 6;           // 0..7
    const int qd = lane >> 4;
    const int ln = lane & 15;
    const int l = blockIdx.x;
    const int bh = l & 127;
    const int b = bh >> 4;
    const int h = bh & 15;
    const int qb = l >> 7;

    const ushortT* Qg = Q + (size_t)bh * 65536;
    const ushortT* Kg = K + (size_t)bh * 65536;
    const ushortT* Vg = Vg_t + (size_t)bh * 65536;
    const float* mrow = mask + b * 1024;
    const float LOG2E = 1.4426950408889634f;
    const float SCL = 0.125f * 1.4426950408889634f;   // fold 1/sqrt(64) and log2e

    // resident Q B-fragments: q = qb*256 + w*32 + g*16 + ln
    short8 qf[2][2];
#pragma unroll
    for (int g = 0; g < 2; g++)
#pragma unroll
        for (int ks = 0; ks < 2; ks++)
            qf[g][ks] = *(const short8*)(Qg + (size_t)(qb * 256 + w * 32 + g * 16 + ln) * 64 + ks * 32 + qd * 8);

    float lst[2] = {0.f, 0.f};        // per-lane partial row-sum (qd-reduce deferred)
    floatx4 accO[2][4];
#pragma unroll
    for (int g = 0; g < 2; g++)
#pragma unroll
        for (int j = 0; j < 4; j++) accO[g][j] = (floatx4){0.f, 0.f, 0.f, 0.f};

    // staging lane geometry (8 waves x 2 chunks each)
    const int ksr = lane >> 3;          // K: s-subrow within 8-row group
    const int kc  = lane & 7;           // K: chunk index (8 x 16B per 128B row)
    const int vdr = lane >> 4;          // V: d-subrow within 4-row group
    const int vcc = lane & 15;          // V: chunk index (16 x 16B per 256B row)

    for (int kt = 0; kt < 8; ++kt) {
        __syncthreads();   // all waves done reading Ks/Vt of kt-1

        // stage K tile [128 s][64 d], chunk g2 of row s at slot g2^(s&7)
#pragma unroll
        for (int ii = 0; ii < 2; ii++) {
            int i = w * 2 + ii;
            int srow = i * 8 + ksr;
            gload_lds16(Kg + (size_t)(kt * 128 + srow) * 64 + (kc ^ ksr) * 8,
                        Ks + i * 512 + lane * 8);
        }
        // stage V^T tile [64 d][128 s], chunk g2 of row d at slot g2^(d&15)
#pragma unroll
        for (int ii = 0; ii < 2; ii++) {
            int i = w * 2 + ii;
            int d = i * 4 + vdr;
            gload_lds16(Vg + (size_t)d * 1024 + kt * 128 + (vcc ^ (d & 15)) * 8,
                        Vt + i * 512 + lane * 8);
        }

        __syncthreads();   // tiles ready

#pragma unroll
        for (int h2 = 0; h2 < 2; ++h2) {
#pragma unroll
            for (int mip = 0; mip < 2; ++mip) {
                // ---- QK^T over this 32-s half (S^T frags: col=q=ln, row=s) ----
                floatx4 sv[2][2];
#pragma unroll
                for (int mi2 = 0; mi2 < 2; mi2++)
#pragma unroll
                    for (int g = 0; g < 2; g++) sv[mi2][g] = (floatx4){0.f, 0.f, 0.f, 0.f};
#pragma unroll
                for (int ks = 0; ks < 2; ks++) {
                    short8 af[2];
#pragma unroll
                    for (int mi2 = 0; mi2 < 2; mi2++)
                        af[mi2] = *(const short8*)&Ks[(h2 * 64 + mip * 32 + mi2 * 16 + ln) * 64 +
                                                      (((ks * 4 + qd) ^ (ln & 7)) * 8)];
#pragma unroll
                    for (int mi2 = 0; mi2 < 2; mi2++)
#pragma unroll
                        for (int g = 0; g < 2; g++)
                            sv[mi2][g] = __builtin_amdgcn_mfma_f32_16x16x32_bf16(af[mi2], qf[g][ks], sv[mi2][g], 0, 0, 0);
                }

                // ---- softmax-lite: p = exp2(s*SCL + mask*LOG2E), write Ps half ----
#pragma unroll
                for (int mi2 = 0; mi2 < 2; mi2++) {
                    floatx4 m4 = *(const floatx4*)(mrow + kt * 128 + h2 * 64 + mip * 32 + mi2 * 16 + qd * 4);
                    floatx4 mm;
                    mm[0] = m4[0] * LOG2E; mm[1] = m4[1] * LOG2E;
                    mm[2] = m4[2] * LOG2E; mm[3] = m4[3] * LOG2E;
#pragma unroll
                    for (int g = 0; g < 2; g++) {
                        float p0 = __builtin_amdgcn_exp2f(sv[mi2][g][0] * SCL + mm[0]);
                        float p1 = __builtin_amdgcn_exp2f(sv[mi2][g][1] * SCL + mm[1]);
                        float p2 = __builtin_amdgcn_exp2f(sv[mi2][g][2] * SCL + mm[2]);
                        float p3 = __builtin_amdgcn_exp2f(sv[mi2][g][3] * SCL + mm[3]);
                        lst[g] += (p0 + p1) + (p2 + p3);
                        uint2 wv;
                        wv.x = pack2_trunc(p0, p1);
                        wv.y = pack2_trunc(p2, p3);
                        *(uint2*)&Ps[w][(g * 16 + ln) * 36 + mi2 * 16 + qd * 4] = wv;
                    }
                }

                // ---- PV for k-slice = this s-half (per-wave Ps, no barrier) ----
                short8 ap[2], bv[4];
#pragma unroll
                for (int g = 0; g < 2; g++)
                    ap[g] = *(const short8*)&Ps[w][(g * 16 + ln) * 36 + qd * 8];
#pragma unroll
                for (int j = 0; j < 4; j++)
                    bv[j] = *(const short8*)&Vt[(j * 16 + ln) * 128 +
                                                (((h2 * 8 + mip * 4 + qd) ^ ln) * 8)];
#pragma unroll
                for (int g = 0; g < 2; g++)
#pragma unroll
                    for (int j = 0; j < 4; j++)
                        accO[g][j] = __builtin_amdgcn_mfma_f32_16x16x32_bf16(ap[g], bv[j], accO[g][j], 0, 0, 0);
            }
        }
    }

    // deferred qd-reduction of row sums (linear, so once at the end)
#pragma unroll
    for (int g = 0; g < 2; g++) {
        lst[g] += __shfl_xor(lst[g], 16, 64);
        lst[g] += __shfl_xor(lst[g], 32, 64);
    }

    // epilogue: divide by l (lane transpose once) and store ctx [b][s=q][h*64+d]
#pragma unroll
    for (int g = 0; g < 2; g++) {
#pragma unroll
        for (int r = 0; r < 4; r++) {
            float lv = __shfl(lst[g], qd * 4 + r, 64);
            float linv = 1.f / lv;
            int q = qb * 256 + w * 32 + g * 16 + qd * 4 + r;
#pragma unroll
            for (int j = 0; j < 4; j++) {
                int d = j * 16 + ln;
                ctx[((size_t)(b * 1024 + q)) * 1024 + h * 64 + d] = f2bf(accO[g][j][r] * linv);
            }
        }
    }
}

// ---------------- LayerNorm (residual pre-added by oproj epilogue) ----------------
__global__ __launch_bounds__(256) void ln_res(const float* __restrict__ Pj,
        const float* __restrict__ gamma, const float* __restrict__ beta, float* __restrict__ out) {
    __shared__ float red[8];
    int row = blockIdx.x;
    int t = threadIdx.x;
    const float4 p4 = ((const float4*)(Pj + (size_t)row * 1024))[t];
    float r0 = p4.x, r1 = p4.y, r2 = p4.z, r3 = p4.w;
    float s = r0 + r1 + r2 + r3;
    float ss = r0 * r0 + r1 * r1 + r2 * r2 + r3 * r3;
#pragma unroll
    for (int o = 1; o < 64; o <<= 1) { s += __shfl_xor(s, o, 64); ss += __shfl_xor(ss, o, 64); }
    int w = t >> 6;
    if ((t & 63) == 0) { red[w] = s; red[4 + w] = ss; }
    __syncthreads();
    s = red[0] + red[1] + red[2] + red[3];
    ss = red[4] + red[5] + red[6] + red[7];
    float mu = s * (1.f / 1024.f);
    float var = ss * (1.f / 1024.f) - mu * mu;
    float inv = rsqrtf(var + 1e-12f);
    const float4 g4 = ((const float4*)gamma)[t];
    const float4 b4 = ((const float4*)beta)[t];
    float4 o4;
    o4.x = (r0 - mu) * inv * g4.x + b4.x;
    o4.y = (r1 - mu) * inv * g4.y + b4.y;
    o4.z = (r2 - mu) * inv * g4.z + b4.z;
    o4.w = (r3 - mu) * inv * g4.w + b4.w;
    ((float4*)(out + (size_t)row * 1024))[t] = o4;
}

extern "C" void kernel_launch(void* const* d_in, const int* in_sizes, int n_in,
                              void* d_out, int out_size, void* d_ws, size_t ws_size,
                              hipStream_t stream) {
    const float* x     = (const float*)d_in[0];
    const float* mask  = (const float*)d_in[1];
    const float* Wq    = (const float*)d_in[2];
    const float* bq    = (const float*)d_in[3];
    const float* Wk    = (const float*)d_in[4];
    const float* bk    = (const float*)d_in[5];
    const float* Wv    = (const float*)d_in[6];
    const float* bv    = (const float*)d_in[7];
    const float* Wo    = (const float*)d_in[8];
    const float* bo    = (const float*)d_in[9];
    const float* gamma = (const float*)d_in[10];
    const float* beta  = (const float*)d_in[11];
    float* out = (float*)d_out;

    char* ws = (char*)d_ws;
    ushortT* Xb   = (ushortT*)(ws);
    ushortT* Wall = (ushortT*)(ws + (16u << 20));  // stacked Wq|Wk|Wv [3072][1024], 6 MB
    ushortT* Wob  = (ushortT*)(ws + (22u << 20));
    ushortT* Qb   = (ushortT*)(ws + (24u << 20));
    ushortT* Kb   = (ushortT*)(ws + (40u << 20));
    ushortT* Vb   = (ushortT*)(ws + (56u << 20));  // V^T [bh][d][s]
    ushortT* Cb   = (ushortT*)(ws);                // ctx reuses Xb
    float*   Pj   = (float*)(ws + (24u << 20));    // fp32 proj reuses Q/K

    cvt_all<<<12288, 256, 0, stream>>>(x, Wq, Wk, Wv, Wo, Xb, Wall, Wob);
    qkv16<<<512, 1024, 0, stream>>>(Xb, Wall, bq, bk, bv, Qb, Kb, Vb);
    attn8<<<512, 512, 0, stream>>>(Qb, Kb, Vb, mask, Cb);
    oproj16<<<256, 1024, 0, stream>>>(Cb, Wob, bo, x, Pj);
    ln_res<<<8192, 256, 0, stream>>>(Pj, gamma, beta, out);
}